// Round 2
// baseline (20811.404 us; speedup 1.0000x reference)
//
#include <hip/hip_runtime.h>

#define HD 512
#define BB 1024
#define TT 512
#define PP 96
#define DIN 32
#define KC_H 16
#define NBLK 256
#define GRPB 16  // blocks per row-group barrier (all 16 jb of one row group)

typedef unsigned short u16;
typedef __attribute__((ext_vector_type(8))) short bf16x8;
typedef __attribute__((ext_vector_type(4))) float f32x4;
typedef __attribute__((address_space(3))) unsigned int lds_u32;
typedef __attribute__((address_space(3))) u16 lds_u16;
typedef __attribute__((address_space(1))) unsigned int glb_u32;

#define WAIT_VM(N) asm volatile("s_waitcnt vmcnt(" #N ")" ::: "memory")
__device__ __forceinline__ void bar_raw() { asm volatile("s_barrier" ::: "memory"); }

__device__ __forceinline__ float bf2f(u16 s) {
  return __uint_as_float(((unsigned)s) << 16);
}
__device__ __forceinline__ u16 f2bf_rne(float f) {
  unsigned u = __float_as_uint(f);
  u += 0x7FFF + ((u >> 16) & 1);
  return (u16)(u >> 16);
}
__device__ __forceinline__ float sigm(float v) { return 1.f / (1.f + __expf(-v)); }
__device__ __forceinline__ float tanh_(float a) {
  return 1.f - 2.f / (__expf(2.f * a) + 1.f);
}

// ---- coherent (L2-bypass) WRITE/poll helpers: sc0 sc1 ----
// h-state READS are now normal cached loads (L1/L2); cross-XCD freshness is
// provided by the agent-scope acquire fence (HW L1+L2 invalidate) in gbar.
__device__ __forceinline__ bf16x8 load_ca16(const u16* p) {  // cached A-load
  bf16x8 r;
  asm volatile("global_load_dwordx4 %0, %1, off" : "=&v"(r) : "v"(p) : "memory");
  return r;
}
__device__ __forceinline__ void store_sc_u16(u16* p, unsigned v) {
  asm volatile("global_store_short %0, %1, off sc0 sc1" :: "v"(p), "v"(v) : "memory");
}
__device__ __forceinline__ void store_sc_f32(float* p, float v) {
  asm volatile("global_store_dword %0, %1, off sc0 sc1" :: "v"(p), "v"(v) : "memory");
}
__device__ __forceinline__ float load_sc_f32w(const float* p) {  // load + full wait
  float v;
  asm volatile("global_load_dword %0, %1, off sc0 sc1\ns_waitcnt vmcnt(0)"
               : "=&v"(v) : "v"(p) : "memory");
  return v;
}
__device__ __forceinline__ unsigned load_sc_u32w(const unsigned* p) {
  unsigned v;
  asm volatile("global_load_dword %0, %1, off sc0 sc1\ns_waitcnt vmcnt(0)"
               : "=&v"(v) : "v"(p) : "memory");
  return v;
}
__device__ __forceinline__ void store_h_sc(u16* H, u16* L, size_t idx, float hv) {
  u16 hi = (u16)(__float_as_uint(hv) >> 16);  // trunc; lo corrects
  u16 lo = f2bf_rne(hv - bf2f(hi));
  store_sc_u16(H + idx, (unsigned)hi);
  store_sc_u16(L + idx, (unsigned)lo);
}

// Pack fp32 weight W[3H x K] into fc-contiguous MFMA B-frag bf16 hi/lo layout:
// group512 = ((jb*KC + kc)*2 + fc)*6 + (g*2 + s);  u16 off = group*512 + lane*8
__global__ void pack_w_kernel(const float* __restrict__ W, int K,
                              u16* __restrict__ out) {
  int tid = blockIdx.x * 256 + threadIdx.x;
  int KC = K >> 5;
  int total = 16 * KC * 2 * 6 * 64;
  if (tid >= total) return;
  int lane = tid & 63;
  int rest = tid >> 6;
  int gs = rest % 6; rest /= 6;
  int fc = rest & 1; rest >>= 1;
  int kc = rest % KC;
  int jb = rest / KC;
  int g = gs >> 1, s = gs & 1;
  int j = jb * 32 + fc * 16 + (lane & 15);
  int k = kc * 32 + (lane >> 4) * 8;
  const float* src = W + (size_t)(g * HD + j) * K + k;
  bf16x8 v;
#pragma unroll
  for (int i = 0; i < 8; ++i) {
    float f = src[i];
    u16 hi = f2bf_rne(f);
    v[i] = (short)((s == 0) ? hi : f2bf_rne(f - bf2f(hi)));
  }
  *(bf16x8*)(out + (size_t)tid * 8) = v;
}

struct AF { bf16x8 h[2]; bf16x8 l[2]; };

__device__ __forceinline__ void fence_af(AF& a) {
  asm volatile("" : "+v"(a.h[0]), "+v"(a.h[1]), "+v"(a.l[0]), "+v"(a.l[1]));
}
// 4 cached loads, exact issue order (volatile) for vmcnt accounting.
// fc-pair waves (same CU) hit L1; same-group blocks on one XCD share L2.
__device__ __forceinline__ void load_af_sc(AF& a, const u16* aH0, const u16* aL0, int kc) {
  const u16* p = aH0 + kc * 32;
  const u16* q = aL0 + kc * 32;
  a.h[0] = load_ca16(p);
  a.h[1] = load_ca16(p + 16 * HD);
  a.l[0] = load_ca16(q);
  a.l[1] = load_ca16(q + 16 * HD);
}

// 18 MFMAs for one kc from an LDS slot (3072 u16: (g*2+s)*512 + lane*8).
__device__ __forceinline__ void mfma_kc_l(const lds_u16* base, int lane,
                                          const AF& a, f32x4* aR, f32x4* aZ, f32x4* aN) {
  typedef __attribute__((address_space(3))) const bf16x8 lds_bf16x8;
  const lds_u16* p = base + lane * 8;
#pragma unroll
  for (int g = 0; g < 3; ++g) {
    f32x4* acc = (g == 0) ? aR : (g == 1) ? aZ : aN;
    bf16x8 whi = *(lds_bf16x8*)(p + (g * 2 + 0) * 512);
    bf16x8 wlo = *(lds_bf16x8*)(p + (g * 2 + 1) * 512);
#pragma unroll
    for (int s = 0; s < 2; ++s) {
      acc[s] = __builtin_amdgcn_mfma_f32_16x16x32_bf16(a.h[s], whi, acc[s], 0, 0, 0);
      acc[s] = __builtin_amdgcn_mfma_f32_16x16x32_bf16(a.l[s], whi, acc[s], 0, 0, 0);
      acc[s] = __builtin_amdgcn_mfma_f32_16x16x32_bf16(a.h[s], wlo, acc[s], 0, 0, 0);
    }
  }
}
// Same from global (x-phase weights, L2-hot, compiler-managed waits).
__device__ __forceinline__ void mfma_kc_g(const u16* base, int lane,
                                          const AF& a, f32x4* aR, f32x4* aZ, f32x4* aN) {
  const u16* p = base + lane * 8;
#pragma unroll
  for (int g = 0; g < 3; ++g) {
    f32x4* acc = (g == 0) ? aR : (g == 1) ? aZ : aN;
    bf16x8 whi = *(const bf16x8*)(p + (g * 2 + 0) * 512);
    bf16x8 wlo = *(const bf16x8*)(p + (g * 2 + 1) * 512);
#pragma unroll
    for (int s = 0; s < 2; ++s) {
      acc[s] = __builtin_amdgcn_mfma_f32_16x16x32_bf16(a.h[s], whi, acc[s], 0, 0, 0);
      acc[s] = __builtin_amdgcn_mfma_f32_16x16x32_bf16(a.l[s], whi, acc[s], 0, 0, 0);
      acc[s] = __builtin_amdgcn_mfma_f32_16x16x32_bf16(a.h[s], wlo, acc[s], 0, 0, 0);
    }
  }
}

// 6 x 1KB LDS-DMA of one 6KB weight chunk (normal cached reads -> L2-hot).
__device__ __forceinline__ void stage6(const u16* src, u16* dst, int lane) {
#pragma unroll
  for (int j = 0; j < 6; ++j)
    __builtin_amdgcn_global_load_lds((const glb_u32*)(src + j * 512 + lane * 8),
                                     (lds_u32*)(dst + j * 512), 16, 0, 0);
}

// K=512 GEMM phase. 4-pair LDS ring (pair = 12KB: matA | matB), prologue 3,
// lead 3. Stager bundle = 12(DUAL)/6 W-DMAs + 4 A-loads; consumer = 4 A-loads.
// Raw s_barrier handoff; manual vmcnt; no __syncthreads, no fences.
template <bool DUAL>
__device__ __forceinline__ void pipe_phase(
    u16* ringfc, const u16* Ahi, const u16* Alo,
    const u16* WA, const u16* WB, int row0w, int lane, bool stg,
    f32x4* aR, f32x4* aZ, f32x4* aN,
    f32x4* bR, f32x4* bZ, f32x4* bN) {
  const int quad = lane >> 4, n16 = lane & 15;
  const u16* aH0 = Ahi + (size_t)(row0w + n16) * HD + quad * 8;
  const u16* aL0 = Alo + (size_t)(row0w + n16) * HD + quad * 8;
  u16* pb[4] = {ringfc, ringfc + 6144, ringfc + 2 * 6144, ringfc + 3 * 6144};
  AF a0, a1, a2, a3;

  auto issueB = [&](int ikc, u16* pair, AF& dst) {
    if (stg) {
      stage6(WA + (size_t)ikc * 6144, pair, lane);
      if constexpr (DUAL) stage6(WB + (size_t)ikc * 6144, pair + 3072, lane);
    }
    load_af_sc(dst, aH0, aL0, ikc);
  };
  auto cons = [&](u16* pair, AF& a) {
    fence_af(a);
    mfma_kc_l((const lds_u16*)pair, lane, a, aR, aZ, aN);
    if constexpr (DUAL) mfma_kc_l((const lds_u16*)(pair + 3072), lane, a, bR, bZ, bN);
  };
  auto wsteady = [&]() {  // oldest of 3 bundles done -> 2 bundles outstanding
    if (stg) { if constexpr (DUAL) WAIT_VM(32); else WAIT_VM(20); }
    else WAIT_VM(8);
  };
  auto wtail1 = [&]() {  // 1 bundle outstanding
    if (stg) { if constexpr (DUAL) WAIT_VM(16); else WAIT_VM(10); }
    else WAIT_VM(4);
  };

  WAIT_VM(0);  // drain unrelated vm-ops so bundle counting is exact
  issueB(0, pb[0], a0);
  issueB(1, pb[1], a1);
  issueB(2, pb[2], a2);
#pragma unroll 1
  for (int kc = 0; kc < 12; kc += 4) {
    wsteady(); bar_raw(); issueB(kc + 3, pb[3], a3); cons(pb[0], a0);
    wsteady(); bar_raw(); issueB(kc + 4, pb[0], a0); cons(pb[1], a1);
    wsteady(); bar_raw(); issueB(kc + 5, pb[1], a1); cons(pb[2], a2);
    wsteady(); bar_raw(); issueB(kc + 6, pb[2], a2); cons(pb[3], a3);
  }
  wsteady(); bar_raw(); issueB(15, pb[3], a3); cons(pb[0], a0);  // kc=12
  wsteady(); bar_raw(); cons(pb[1], a1);                         // kc=13
  wtail1();  bar_raw(); cons(pb[2], a2);                         // kc=14
  WAIT_VM(0); bar_raw(); cons(pb[3], a3);                        // kc=15
}

// x-phase for encoder L0: fp32 x[B,T,32], K=32, weights/x normal (L2-hot).
__device__ __forceinline__ void x_phase(const float* x, int t, const u16* Wp,
                                        int jb, int fc, int row0w, int lane,
                                        f32x4* aR, f32x4* aZ, f32x4* aN) {
  const int quad = lane >> 4, n16 = lane & 15;
  AF ax;
#pragma unroll
  for (int s = 0; s < 2; ++s) {
    const float* xp = x + (size_t)(row0w + s * 16 + n16) * (TT * DIN) +
                      (size_t)t * DIN + quad * 8;
    f32x4 v0 = *(const f32x4*)xp;
    f32x4 v1 = *(const f32x4*)(xp + 4);
    bf16x8 hi, lo;
#pragma unroll
    for (int i = 0; i < 8; ++i) {
      float f = (i < 4) ? v0[i] : v1[i - 4];
      u16 h = (u16)(__float_as_uint(f) >> 16);
      hi[i] = (short)h;
      lo[i] = (short)f2bf_rne(f - bf2f(h));
    }
    ax.h[s] = hi;
    ax.l[s] = lo;
  }
  mfma_kc_g(Wp + ((size_t)jb * 2 + fc) * 3072, lane, ax, aR, aZ, aN);
}

// Row-group barrier (16 blocks sharing row0). After detection, an agent-scope
// acquire fence invalidates L1+L2 so subsequent NORMAL cached loads of h-state
// (written cross-XCD via sc0sc1 stores) observe fresh data and then serve the
// fc-pair / same-XCD redundancy from L1/L2 instead of hammering the LLC with
// 16-B coherent reads.
__device__ __forceinline__ void gbar(unsigned* gen, unsigned target) {
  WAIT_VM(0);  // all this wave's sc1 stores / atomics globally visible
  __syncthreads();
  if (threadIdx.x == 0) {
    atomicAdd(gen, 1u);  // device-scope by default
    while (load_sc_u32w(gen) < target) __builtin_amdgcn_s_sleep(2);
  }
  __syncthreads();
  __builtin_amdgcn_fence(__ATOMIC_ACQUIRE, "agent");  // HW L1+L2 invalidate
}

// GRU epilogue with register-resident own-tile h (ho never re-read from mem).
__device__ __forceinline__ void gru_epi_reg(
    const float* bi, const float* bh, float (*ht)[4],
    u16* hnH, u16* hnL, int col, int row0w, int quad,
    const f32x4* aR, const f32x4* aZ, const f32x4* aNX, const f32x4* aNH) {
  const float bir = bi[col],          bhr = bh[col];
  const float biz = bi[HD + col],     bhz = bh[HD + col];
  const float bin = bi[2 * HD + col], bhn = bh[2 * HD + col];
#pragma unroll
  for (int s = 0; s < 2; ++s)
#pragma unroll
    for (int r = 0; r < 4; ++r) {
      const int row = row0w + s * 16 + quad * 4 + r;
      const size_t idx = (size_t)row * HD + col;
      float rr = sigm(aR[s][r] + bir + bhr);
      float zz = sigm(aZ[s][r] + biz + bhz);
      float nn = tanh_(aNX[s][r] + bin + rr * (aNH[s][r] + bhn));
      float hv = (1.f - zz) * nn + zz * ht[s][r];
      ht[s][r] = hv;
      store_h_sc(hnH, hnL, idx, hv);
    }
}

__global__ __launch_bounds__(256, 1)
void gru_persistent_kernel(
    const float* x,
    const u16* pkX0, const u16* pkH0, const float* bi0, const float* bh0,
    const u16* pkX1, const u16* pkH1, const float* bi1, const float* bh1,
    const u16* pkD0H, const float* dbi0, const float* dbh0, const float* dW0,
    const u16* pkD1I, const u16* pkD1H, const float* dbi1, const float* dbh1,
    const float* outW, const float* outb, const float* dstart,
    u16* h1aH, u16* h1aL, u16* h1bH, u16* h1bL,
    u16* h2aH, u16* h2aL, u16* h2bH, u16* h2bL,
    float* yfull, float* dout, unsigned* gen) {
  __shared__ u16 ring[2][4][6144];  // 96 KB: per-fc 4-pair weight ring
  const int b = blockIdx.x;
  const int jb = (b & 7) * 2 + ((b >> 3) & 1);  // XCD-local jb
  const int row0 = (b >> 4) * 64;
  const int tid = threadIdx.x, wave = tid >> 6, lane = tid & 63;
  const int quad = lane >> 4, n16 = lane & 15;
  const int fc = wave & 1, rowg = wave >> 1;
  const bool stg = (rowg == 0);
  const int row0w = row0 + rowg * 32;
  const int col = jb * 32 + fc * 16 + n16;
  u16* ringfc = &ring[fc][0][0];
  const f32x4 z4 = {0.f, 0.f, 0.f, 0.f};
  const size_t woff = ((size_t)jb * KC_H * 2 + fc) * 3072;  // kc stride 6144
  // Per-row-group barrier counter: one u32 per group, 256-B line separation.
  unsigned* geng = gen + ((b >> 4) << 6);

  u16 *h1cH = h1aH, *h1cL = h1aL, *h1nH = h1bH, *h1nL = h1bL;
  u16 *h2cH = h2aH, *h2cL = h2aL, *h2nH = h2bH, *h2nL = h2bL;
  float ht1[2][4] = {{0, 0, 0, 0}, {0, 0, 0, 0}};  // own h1 tile (regs)
  float ht2[2][4] = {{0, 0, 0, 0}, {0, 0, 0, 0}};  // own h2 tile (regs)
  unsigned it = 0;

  // ---- encoder: 513 skewed phases; fused h1c stream feeds L0-h AND L1-x ----
  for (int k = 0; k <= TT; ++k) {
    f32x4 R0[2] = {z4, z4}, Z0[2] = {z4, z4}, NX0[2] = {z4, z4}, NH0[2] = {z4, z4};
    f32x4 R1[2] = {z4, z4}, Z1[2] = {z4, z4}, NX1[2] = {z4, z4}, NH1[2] = {z4, z4};
    if (k > 0 && k < TT) {
      pipe_phase<true>(ringfc, h1cH, h1cL, pkH0 + woff, pkX1 + woff,
                       row0w, lane, stg, R0, Z0, NH0, R1, Z1, NX1);
    } else if (k == 0) {
      pipe_phase<false>(ringfc, h1cH, h1cL, pkH0 + woff, pkH0 + woff,
                        row0w, lane, stg, R0, Z0, NH0, R1, Z1, NX1);
    } else {  // k == TT
      pipe_phase<false>(ringfc, h1cH, h1cL, pkX1 + woff, pkX1 + woff,
                        row0w, lane, stg, R1, Z1, NX1, R0, Z0, NH0);
    }
    if (k < TT) {
      x_phase(x, k, pkX0, jb, fc, row0w, lane, R0, Z0, NX0);
      gru_epi_reg(bi0, bh0, ht1, h1nH, h1nL, col, row0w, quad, R0, Z0, NX0, NH0);
    }
    if (k > 0) {
      pipe_phase<false>(ringfc, h2cH, h2cL, pkH1 + woff, pkH1 + woff,
                        row0w, lane, stg, R1, Z1, NH1, R0, Z0, NX0);
      gru_epi_reg(bi1, bh1, ht2, h2nH, h2nL, col, row0w, quad, R1, Z1, NX1, NH1);
    }
    gbar(geng, GRPB * (++it));
    if (k < TT) { u16* t0 = h1cH; h1cH = h1nH; h1nH = t0;
                  u16* t1 = h1cL; h1cL = h1nL; h1nL = t1; }
    if (k > 0)  { u16* t0 = h2cH; h2cH = h2nH; h2nH = t0;
                  u16* t1 = h2cL; h2cL = h2nL; h2nL = t1; }
  }

  // ---- decoder: 96 steps x (L0, L1); y via atomics into yfull[2][BB] ----
  for (int t = 0; t < PP; ++t) {
    {  // dec L0
      f32x4 R[2] = {z4, z4}, Z[2] = {z4, z4}, NH[2] = {z4, z4};
      f32x4 D0[2] = {z4, z4}, D1[2] = {z4, z4}, D2[2] = {z4, z4};
      pipe_phase<false>(ringfc, h1cH, h1cL, pkD0H + woff, pkD0H + woff,
                        row0w, lane, stg, R, Z, NH, D0, D1, D2);
      float yl[2][4] = {{0, 0, 0, 0}, {0, 0, 0, 0}};
      if (t > 0) {
        const float* yb = yfull + ((t - 1) & 1) * BB;
#pragma unroll
        for (int s = 0; s < 2; ++s)
#pragma unroll
          for (int r = 0; r < 4; ++r) {
            const float* p = yb + (row0w + s * 16 + quad * 4 + r);
            asm volatile("global_load_dword %0, %1, off sc0 sc1"
                         : "=&v"(yl[s][r]) : "v"(p) : "memory");
          }
        WAIT_VM(0);
#pragma unroll
        for (int s = 0; s < 2; ++s)
#pragma unroll
          for (int r = 0; r < 4; ++r)
            asm volatile("" : "+v"(yl[s][r]));
      }
      const float ds0 = dstart[0], ob0 = outb[0];
      const float bir = dbi0[col],          bhr = dbh0[col];
      const float biz = dbi0[HD + col],     bhz = dbh0[HD + col];
      const float bin = dbi0[2 * HD + col], bhn = dbh0[2 * HD + col];
      const float w0r = dW0[col], w0z = dW0[HD + col], w0n = dW0[2 * HD + col];
#pragma unroll
      for (int s = 0; s < 2; ++s)
#pragma unroll
        for (int r = 0; r < 4; ++r) {
          const int row = row0w + s * 16 + quad * 4 + r;
          const size_t idx = (size_t)row * HD + col;
          float yv = (t == 0) ? ds0 : (ob0 + yl[s][r]);
          if (t > 0 && jb == 0 && fc == 0 && n16 == 0)
            dout[(size_t)row * PP + (t - 1)] = yv;
          float rr = sigm(R[s][r] + bir + bhr + yv * w0r);
          float zz = sigm(Z[s][r] + biz + bhz + yv * w0z);
          float nn = tanh_(bin + yv * w0n + rr * (NH[s][r] + bhn));
          float hv = (1.f - zz) * nn + zz * ht1[s][r];
          ht1[s][r] = hv;
          store_h_sc(h1nH, h1nL, idx, hv);
        }
    }
    gbar(geng, GRPB * (++it));
    {  // dec L1: x-phase (d1 new) + h-phase (d2); y partials via atomicAdd
      f32x4 R[2] = {z4, z4}, Z[2] = {z4, z4}, NX[2] = {z4, z4}, NH[2] = {z4, z4};
      f32x4 D0[2] = {z4, z4}, D1[2] = {z4, z4}, D2[2] = {z4, z4};
      pipe_phase<false>(ringfc, h1nH, h1nL, pkD1I + woff, pkD1I + woff,
                        row0w, lane, stg, R, Z, NX, D0, D1, D2);
      pipe_phase<false>(ringfc, h2cH, h2cL, pkD1H + woff, pkD1H + woff,
                        row0w, lane, stg, R, Z, NH, D0, D1, D2);
      const float bir = dbi1[col],          bhr = dbh1[col];
      const float biz = dbi1[HD + col],     bhz = dbh1[HD + col];
      const float bin = dbi1[2 * HD + col], bhn = dbh1[2 * HD + col];
      const float wo = outW[col];
      float* yw = yfull + (t & 1) * BB;
      float* yz = yfull + ((t - 1) & 1) * BB;
#pragma unroll
      for (int s = 0; s < 2; ++s)
#pragma unroll
        for (int r = 0; r < 4; ++r) {
          const int row = row0w + s * 16 + quad * 4 + r;
          const size_t idx = (size_t)row * HD + col;
          float rr = sigm(R[s][r] + bir + bhr);
          float zz = sigm(Z[s][r] + biz + bhz);
          float nn = tanh_(NX[s][r] + bin + rr * (NH[s][r] + bhn));
          float hv = (1.f - zz) * nn + zz * ht2[s][r];
          ht2[s][r] = hv;
          store_h_sc(h2nH, h2nL, idx, hv);
          float v = hv * wo;
#pragma unroll
          for (int off = 1; off < 16; off <<= 1) v += __shfl_xor(v, off, 16);
          if (n16 == 0) {
            atomicAdd(yw + row, v);
            // zero last parity (read by dec L0 this iter; rewritten at t+1)
            if (t > 0 && jb == 0 && fc == 0) store_sc_f32(yz + row, 0.f);
          }
        }
    }
    gbar(geng, GRPB * (++it));
    { u16* t0 = h1cH; h1cH = h1nH; h1nH = t0;
      u16* t1 = h1cL; h1cL = h1nL; h1nL = t1; }
    { u16* t0 = h2cH; h2cH = h2nH; h2nH = t0;
      u16* t1 = h2cL; h2cL = h2nL; h2nL = t1; }
  }

  // ---- finalize: y(P-1), group-local (each group's jb==0 block owns its
  // 64 rows; last gbar guarantees peer atomicAdds are visible) ----
  if ((b & 15) == 0 && tid < 64) {
    int row = row0 + tid;
    float v = load_sc_f32w(yfull + ((PP - 1) & 1) * BB + row);
    dout[(size_t)row * PP + (PP - 1)] = outb[0] + v;
  }
}

extern "C" void kernel_launch(void* const* d_in, const int* in_sizes, int n_in,
                              void* d_out, int out_size, void* d_ws, size_t ws_size,
                              hipStream_t stream) {
  const float* x      = (const float*)d_in[0];
  const float* eW_ih0 = (const float*)d_in[1];
  const float* eW_hh0 = (const float*)d_in[2];
  const float* eb_ih0 = (const float*)d_in[3];
  const float* eb_hh0 = (const float*)d_in[4];
  const float* eW_ih1 = (const float*)d_in[5];
  const float* eW_hh1 = (const float*)d_in[6];
  const float* eb_ih1 = (const float*)d_in[7];
  const float* eb_hh1 = (const float*)d_in[8];
  const float* dW_ih0 = (const float*)d_in[9];
  const float* dW_hh0 = (const float*)d_in[10];
  const float* db_ih0 = (const float*)d_in[11];
  const float* db_hh0 = (const float*)d_in[12];
  const float* dW_ih1 = (const float*)d_in[13];
  const float* dW_hh1 = (const float*)d_in[14];
  const float* db_ih1 = (const float*)d_in[15];
  const float* db_hh1 = (const float*)d_in[16];
  const float* outW   = (const float*)d_in[17];
  const float* outb   = (const float*)d_in[18];
  const float* dstart = (const float*)d_in[19];
  float* out = (float*)d_out;

  char* w = (char*)d_ws;
  size_t off = 0;
  auto carve = [&](size_t bytes) -> void* {
    void* p = w + off;
    off = (off + bytes + 255) & ~(size_t)255;
    return p;
  };
  u16* h1aH = (u16*)carve((size_t)BB * HD * 2); u16* h1aL = (u16*)carve((size_t)BB * HD * 2);
  u16* h1bH = (u16*)carve((size_t)BB * HD * 2); u16* h1bL = (u16*)carve((size_t)BB * HD * 2);
  u16* h2aH = (u16*)carve((size_t)BB * HD * 2); u16* h2aL = (u16*)carve((size_t)BB * HD * 2);
  u16* h2bH = (u16*)carve((size_t)BB * HD * 2); u16* h2bL = (u16*)carve((size_t)BB * HD * 2);
  float* yfull = (float*)carve((size_t)2 * BB * 4);
  unsigned* gen = (unsigned*)carve(4096);  // 16 group counters, 256-B stride
  auto carve_pack = [&](int K) -> u16* {
    return (u16*)carve((size_t)3 * HD * K * 2 * 2);
  };
  u16* pk_e0ih = carve_pack(DIN);
  u16* pk_e0hh = carve_pack(HD);
  u16* pk_e1ih = carve_pack(HD);
  u16* pk_e1hh = carve_pack(HD);
  u16* pk_d0hh = carve_pack(HD);
  u16* pk_d1ih = carve_pack(HD);
  u16* pk_d1hh = carve_pack(HD);

  hipMemsetAsync(h1aH, 0, (size_t)BB * HD * 2, stream);
  hipMemsetAsync(h1aL, 0, (size_t)BB * HD * 2, stream);
  hipMemsetAsync(h2aH, 0, (size_t)BB * HD * 2, stream);
  hipMemsetAsync(h2aL, 0, (size_t)BB * HD * 2, stream);
  hipMemsetAsync(yfull, 0, (size_t)2 * BB * 4, stream);
  hipMemsetAsync(gen, 0, 4096, stream);

  auto pack = [&](const float* W, int K, u16* dst) {
    int total = 16 * (K >> 5) * 2 * 6 * 64;
    pack_w_kernel<<<(total + 255) / 256, 256, 0, stream>>>(W, K, dst);
  };
  pack(eW_ih0, DIN, pk_e0ih);
  pack(eW_hh0, HD, pk_e0hh);
  pack(eW_ih1, HD, pk_e1ih);
  pack(eW_hh1, HD, pk_e1hh);
  pack(dW_hh0, HD, pk_d0hh);
  pack(dW_ih1, HD, pk_d1ih);
  pack(dW_hh1, HD, pk_d1hh);

  gru_persistent_kernel<<<NBLK, 256, 0, stream>>>(
      x, pk_e0ih, pk_e0hh, eb_ih0, eb_hh0,
      pk_e1ih, pk_e1hh, eb_ih1, eb_hh1,
      pk_d0hh, db_ih0, db_hh0, dW_ih0,
      pk_d1ih, pk_d1hh, db_ih1, db_hh1,
      outW, outb, dstart,
      h1aH, h1aL, h1bH, h1bL, h2aH, h2aL, h2bH, h2bL,
      yfull, out, gen);
}

// Round 3
// 20294.423 us; speedup vs baseline: 1.0255x; 1.0255x over previous
//
#include <hip/hip_runtime.h>

#define HD 512
#define BB 1024
#define TT 512
#define PP 96
#define DIN 32
#define KC_H 16
#define NBLK 256
#define GRPB 16  // blocks per row-group barrier (all 16 jb of one row group)

typedef unsigned short u16;
typedef __attribute__((ext_vector_type(8))) short bf16x8;
typedef __attribute__((ext_vector_type(4))) float f32x4;
typedef __attribute__((address_space(3))) unsigned int lds_u32;
typedef __attribute__((address_space(3))) u16 lds_u16;
typedef __attribute__((address_space(1))) unsigned int glb_u32;

#define WAIT_VM(N) asm volatile("s_waitcnt vmcnt(" #N ")" ::: "memory")
__device__ __forceinline__ void bar_raw() { asm volatile("s_barrier" ::: "memory"); }

__device__ __forceinline__ float bf2f(u16 s) {
  return __uint_as_float(((unsigned)s) << 16);
}
__device__ __forceinline__ u16 f2bf_rne(float f) {
  unsigned u = __float_as_uint(f);
  u += 0x7FFF + ((u >> 16) & 1);
  return (u16)(u >> 16);
}
__device__ __forceinline__ float sigm(float v) { return 1.f / (1.f + __expf(-v)); }
__device__ __forceinline__ float tanh_(float a) {
  return 1.f - 2.f / (__expf(2.f * a) + 1.f);
}

// ---- coherent (L2-bypass) access helpers: sc0 sc1 ----
__device__ __forceinline__ bf16x8 load_sc16(const u16* p) {
  bf16x8 r;
  asm volatile("global_load_dwordx4 %0, %1, off sc0 sc1" : "=&v"(r) : "v"(p) : "memory");
  return r;
}
__device__ __forceinline__ void store_sc_u16(u16* p, unsigned v) {
  asm volatile("global_store_short %0, %1, off sc0 sc1" :: "v"(p), "v"(v) : "memory");
}
__device__ __forceinline__ void store_sc_f32(float* p, float v) {
  asm volatile("global_store_dword %0, %1, off sc0 sc1" :: "v"(p), "v"(v) : "memory");
}
__device__ __forceinline__ float load_sc_f32w(const float* p) {  // load + full wait
  float v;
  asm volatile("global_load_dword %0, %1, off sc0 sc1\ns_waitcnt vmcnt(0)"
               : "=&v"(v) : "v"(p) : "memory");
  return v;
}
__device__ __forceinline__ unsigned load_sc_u32w(const unsigned* p) {
  unsigned v;
  asm volatile("global_load_dword %0, %1, off sc0 sc1\ns_waitcnt vmcnt(0)"
               : "=&v"(v) : "v"(p) : "memory");
  return v;
}
__device__ __forceinline__ void store_h_sc(u16* H, u16* L, size_t idx, float hv) {
  u16 hi = (u16)(__float_as_uint(hv) >> 16);  // trunc; lo corrects
  u16 lo = f2bf_rne(hv - bf2f(hi));
  store_sc_u16(H + idx, (unsigned)hi);
  store_sc_u16(L + idx, (unsigned)lo);
}

// Pack fp32 weight W[3H x K] into fc-contiguous MFMA B-frag bf16 hi/lo layout:
// group512 = ((jb*KC + kc)*2 + fc)*6 + (g*2 + s);  u16 off = group*512 + lane*8
__global__ void pack_w_kernel(const float* __restrict__ W, int K,
                              u16* __restrict__ out) {
  int tid = blockIdx.x * 256 + threadIdx.x;
  int KC = K >> 5;
  int total = 16 * KC * 2 * 6 * 64;
  if (tid >= total) return;
  int lane = tid & 63;
  int rest = tid >> 6;
  int gs = rest % 6; rest /= 6;
  int fc = rest & 1; rest >>= 1;
  int kc = rest % KC;
  int jb = rest / KC;
  int g = gs >> 1, s = gs & 1;
  int j = jb * 32 + fc * 16 + (lane & 15);
  int k = kc * 32 + (lane >> 4) * 8;
  const float* src = W + (size_t)(g * HD + j) * K + k;
  bf16x8 v;
#pragma unroll
  for (int i = 0; i < 8; ++i) {
    float f = src[i];
    u16 hi = f2bf_rne(f);
    v[i] = (short)((s == 0) ? hi : f2bf_rne(f - bf2f(hi)));
  }
  *(bf16x8*)(out + (size_t)tid * 8) = v;
}

// 8-wave layout: each wave owns a 16-row x 16-col output tile.
struct AF { bf16x8 h; bf16x8 l; };

__device__ __forceinline__ void fence_af(AF& a) {
  asm volatile("" : "+v"(a.h), "+v"(a.l));
}
// 2 sc1 loads, exact issue order (volatile) for vmcnt accounting.
__device__ __forceinline__ void load_af_sc(AF& a, const u16* aH0, const u16* aL0, int kc) {
  a.h = load_sc16(aH0 + kc * 32);
  a.l = load_sc16(aL0 + kc * 32);
}

// 9 MFMAs for one kc from an LDS slot (3072 u16: (g*2+s)*512 + lane*8).
__device__ __forceinline__ void mfma_kc_l(const lds_u16* base, int lane, const AF& a,
                                          f32x4& aR, f32x4& aZ, f32x4& aN) {
  typedef __attribute__((address_space(3))) const bf16x8 lds_bf16x8;
  const lds_u16* p = base + lane * 8;
#pragma unroll
  for (int g = 0; g < 3; ++g) {
    f32x4* acc = (g == 0) ? &aR : (g == 1) ? &aZ : &aN;
    bf16x8 whi = *(lds_bf16x8*)(p + (g * 2 + 0) * 512);
    bf16x8 wlo = *(lds_bf16x8*)(p + (g * 2 + 1) * 512);
    *acc = __builtin_amdgcn_mfma_f32_16x16x32_bf16(a.h, whi, *acc, 0, 0, 0);
    *acc = __builtin_amdgcn_mfma_f32_16x16x32_bf16(a.l, whi, *acc, 0, 0, 0);
    *acc = __builtin_amdgcn_mfma_f32_16x16x32_bf16(a.h, wlo, *acc, 0, 0, 0);
  }
}
// Same from global (x-phase weights, L2-hot, compiler-managed waits).
__device__ __forceinline__ void mfma_kc_g(const u16* base, int lane, const AF& a,
                                          f32x4& aR, f32x4& aZ, f32x4& aN) {
  const u16* p = base + lane * 8;
#pragma unroll
  for (int g = 0; g < 3; ++g) {
    f32x4* acc = (g == 0) ? &aR : (g == 1) ? &aZ : &aN;
    bf16x8 whi = *(const bf16x8*)(p + (g * 2 + 0) * 512);
    bf16x8 wlo = *(const bf16x8*)(p + (g * 2 + 1) * 512);
    *acc = __builtin_amdgcn_mfma_f32_16x16x32_bf16(a.h, whi, *acc, 0, 0, 0);
    *acc = __builtin_amdgcn_mfma_f32_16x16x32_bf16(a.l, whi, *acc, 0, 0, 0);
    *acc = __builtin_amdgcn_mfma_f32_16x16x32_bf16(a.h, wlo, *acc, 0, 0, 0);
  }
}

// 6 x 1KB LDS-DMA of one 6KB weight chunk (normal cached reads -> L2-hot).
__device__ __forceinline__ void stage6(const u16* src, u16* dst, int lane) {
#pragma unroll
  for (int j = 0; j < 6; ++j)
    __builtin_amdgcn_global_load_lds((const glb_u32*)(src + j * 512 + lane * 8),
                                     (lds_u32*)(dst + j * 512), 16, 0, 0);
}

// K=512 GEMM phase. 4-pair LDS ring (pair = 12KB: matA | matB), prologue 3,
// lead 3. Bundles/kc: stager = 12(DUAL)/6 W-DMAs + 2 A-loads; consumer = 2
// A-loads. Raw s_barrier handoff; manual vmcnt; no __syncthreads, no fences.
template <bool DUAL>
__device__ __forceinline__ void pipe_phase(
    u16* ringfc, const u16* Ahi, const u16* Alo,
    const u16* WA, const u16* WB, int row0w, int lane, bool stg,
    f32x4& aR, f32x4& aZ, f32x4& aN,
    f32x4& bR, f32x4& bZ, f32x4& bN) {
  const int quad = lane >> 4, n16 = lane & 15;
  const u16* aH0 = Ahi + (size_t)(row0w + n16) * HD + quad * 8;
  const u16* aL0 = Alo + (size_t)(row0w + n16) * HD + quad * 8;
  u16* pb[4] = {ringfc, ringfc + 6144, ringfc + 2 * 6144, ringfc + 3 * 6144};
  AF a0, a1, a2, a3;

  auto issueB = [&](int ikc, u16* pair, AF& dst) {
    if (stg) {
      stage6(WA + (size_t)ikc * 6144, pair, lane);
      if constexpr (DUAL) stage6(WB + (size_t)ikc * 6144, pair + 3072, lane);
    }
    load_af_sc(dst, aH0, aL0, ikc);
  };
  auto cons = [&](u16* pair, AF& a) {
    fence_af(a);
    mfma_kc_l((const lds_u16*)pair, lane, a, aR, aZ, aN);
    if constexpr (DUAL) mfma_kc_l((const lds_u16*)(pair + 3072), lane, a, bR, bZ, bN);
  };
  auto wsteady = [&]() {  // oldest of 3 bundles done -> 2 bundles outstanding
    if (stg) { if constexpr (DUAL) WAIT_VM(28); else WAIT_VM(16); }
    else WAIT_VM(4);
  };
  auto wtail1 = [&]() {  // 1 bundle outstanding
    if (stg) { if constexpr (DUAL) WAIT_VM(14); else WAIT_VM(8); }
    else WAIT_VM(2);
  };

  WAIT_VM(0);  // drain unrelated vm-ops so bundle counting is exact
  issueB(0, pb[0], a0);
  issueB(1, pb[1], a1);
  issueB(2, pb[2], a2);
#pragma unroll 1
  for (int kc = 0; kc < 12; kc += 4) {
    wsteady(); bar_raw(); issueB(kc + 3, pb[3], a3); cons(pb[0], a0);
    wsteady(); bar_raw(); issueB(kc + 4, pb[0], a0); cons(pb[1], a1);
    wsteady(); bar_raw(); issueB(kc + 5, pb[1], a1); cons(pb[2], a2);
    wsteady(); bar_raw(); issueB(kc + 6, pb[2], a2); cons(pb[3], a3);
  }
  wsteady(); bar_raw(); issueB(15, pb[3], a3); cons(pb[0], a0);  // kc=12
  wsteady(); bar_raw(); cons(pb[1], a1);                         // kc=13
  wtail1();  bar_raw(); cons(pb[2], a2);                         // kc=14
  WAIT_VM(0); bar_raw(); cons(pb[3], a3);                        // kc=15
}

// x-phase for encoder L0: fp32 x[B,T,32], K=32, weights/x normal (L2-hot).
__device__ __forceinline__ void x_phase(const float* x, int t, const u16* Wp,
                                        int jb, int fc, int row0w, int lane,
                                        f32x4& aR, f32x4& aZ, f32x4& aN) {
  const int quad = lane >> 4, n16 = lane & 15;
  AF ax;
  const float* xp = x + (size_t)(row0w + n16) * (TT * DIN) +
                    (size_t)t * DIN + quad * 8;
  f32x4 v0 = *(const f32x4*)xp;
  f32x4 v1 = *(const f32x4*)(xp + 4);
  bf16x8 hi, lo;
#pragma unroll
  for (int i = 0; i < 8; ++i) {
    float f = (i < 4) ? v0[i] : v1[i - 4];
    u16 h = (u16)(__float_as_uint(f) >> 16);
    hi[i] = (short)h;
    lo[i] = (short)f2bf_rne(f - bf2f(h));
  }
  ax.h = hi;
  ax.l = lo;
  mfma_kc_g(Wp + ((size_t)jb * 2 + fc) * 3072, lane, ax, aR, aZ, aN);
}

// Row-group barrier (16 blocks sharing row0): every cross-block dependency in
// this kernel is row-preserving (h1/h2/yfull reads touch only the block's own
// 64 rows, written by the 16 same-row0 blocks), so a 16-block barrier on a
// private counter line suffices. No cache invalidation: sc1 traffic coherent.
__device__ __forceinline__ void gbar(unsigned* gen, unsigned target) {
  WAIT_VM(0);  // all this wave's sc1 stores / atomics globally visible
  __syncthreads();
  if (threadIdx.x == 0) {
    atomicAdd(gen, 1u);  // device-scope by default
    while (load_sc_u32w(gen) < target) __builtin_amdgcn_s_sleep(2);
  }
  __syncthreads();
}

// GRU epilogue with register-resident own-tile h (ho never re-read from mem).
__device__ __forceinline__ void gru_epi_reg(
    const float* bi, const float* bh, float* ht,
    u16* hnH, u16* hnL, int col, int row0w, int quad,
    const f32x4& aR, const f32x4& aZ, const f32x4& aNX, const f32x4& aNH) {
  const float bir = bi[col],          bhr = bh[col];
  const float biz = bi[HD + col],     bhz = bh[HD + col];
  const float bin = bi[2 * HD + col], bhn = bh[2 * HD + col];
#pragma unroll
  for (int r = 0; r < 4; ++r) {
    const int row = row0w + quad * 4 + r;
    const size_t idx = (size_t)row * HD + col;
    float rr = sigm(aR[r] + bir + bhr);
    float zz = sigm(aZ[r] + biz + bhz);
    float nn = tanh_(aNX[r] + bin + rr * (aNH[r] + bhn));
    float hv = (1.f - zz) * nn + zz * ht[r];
    ht[r] = hv;
    store_h_sc(hnH, hnL, idx, hv);
  }
}

__global__ __launch_bounds__(512, 2)
void gru_persistent_kernel(
    const float* x,
    const u16* pkX0, const u16* pkH0, const float* bi0, const float* bh0,
    const u16* pkX1, const u16* pkH1, const float* bi1, const float* bh1,
    const u16* pkD0H, const float* dbi0, const float* dbh0, const float* dW0,
    const u16* pkD1I, const u16* pkD1H, const float* dbi1, const float* dbh1,
    const float* outW, const float* outb, const float* dstart,
    u16* h1aH, u16* h1aL, u16* h1bH, u16* h1bL,
    u16* h2aH, u16* h2aL, u16* h2bH, u16* h2bL,
    float* yfull, float* dout, unsigned* gen) {
  __shared__ u16 ring[2][4][6144];  // 96 KB: per-fc 4-pair weight ring
  const int b = blockIdx.x;
  const int jb = (b & 7) * 2 + ((b >> 3) & 1);  // XCD-local jb
  const int row0 = (b >> 4) * 64;
  const int tid = threadIdx.x, wave = tid >> 6, lane = tid & 63;
  const int quad = lane >> 4, n16 = lane & 15;
  const int fc = wave & 1, rowg = wave >> 1;  // 8 waves: 4 rowg x 2 fc
  const bool stg = (rowg == 0);
  const int row0w = row0 + rowg * 16;
  const int col = jb * 32 + fc * 16 + n16;
  u16* ringfc = &ring[fc][0][0];
  const f32x4 z4 = {0.f, 0.f, 0.f, 0.f};
  const size_t woff = ((size_t)jb * KC_H * 2 + fc) * 3072;  // kc stride 6144
  // Per-row-group barrier counter: one u32 per group, 256-B line separation.
  unsigned* geng = gen + ((b >> 4) << 6);

  u16 *h1cH = h1aH, *h1cL = h1aL, *h1nH = h1bH, *h1nL = h1bL;
  u16 *h2cH = h2aH, *h2cL = h2aL, *h2nH = h2bH, *h2nL = h2bL;
  float ht1[4] = {0, 0, 0, 0};  // own h1 tile (regs)
  float ht2[4] = {0, 0, 0, 0};  // own h2 tile (regs)
  unsigned it = 0;

  // ---- encoder: 513 skewed phases; fused h1c stream feeds L0-h AND L1-x ----
  for (int k = 0; k <= TT; ++k) {
    f32x4 R0 = z4, Z0 = z4, NX0 = z4, NH0 = z4;
    f32x4 R1 = z4, Z1 = z4, NX1 = z4, NH1 = z4;
    if (k > 0 && k < TT) {
      pipe_phase<true>(ringfc, h1cH, h1cL, pkH0 + woff, pkX1 + woff,
                       row0w, lane, stg, R0, Z0, NH0, R1, Z1, NX1);
    } else if (k == 0) {
      pipe_phase<false>(ringfc, h1cH, h1cL, pkH0 + woff, pkH0 + woff,
                        row0w, lane, stg, R0, Z0, NH0, R1, Z1, NX1);
    } else {  // k == TT
      pipe_phase<false>(ringfc, h1cH, h1cL, pkX1 + woff, pkX1 + woff,
                        row0w, lane, stg, R1, Z1, NX1, R0, Z0, NH0);
    }
    if (k < TT) {
      x_phase(x, k, pkX0, jb, fc, row0w, lane, R0, Z0, NX0);
      gru_epi_reg(bi0, bh0, ht1, h1nH, h1nL, col, row0w, quad, R0, Z0, NX0, NH0);
    }
    if (k > 0) {
      pipe_phase<false>(ringfc, h2cH, h2cL, pkH1 + woff, pkH1 + woff,
                        row0w, lane, stg, R1, Z1, NH1, R0, Z0, NX0);
      gru_epi_reg(bi1, bh1, ht2, h2nH, h2nL, col, row0w, quad, R1, Z1, NX1, NH1);
    }
    gbar(geng, GRPB * (++it));
    if (k < TT) { u16* t0 = h1cH; h1cH = h1nH; h1nH = t0;
                  u16* t1 = h1cL; h1cL = h1nL; h1nL = t1; }
    if (k > 0)  { u16* t0 = h2cH; h2cH = h2nH; h2nH = t0;
                  u16* t1 = h2cL; h2cL = h2nL; h2nL = t1; }
  }

  // ---- decoder: 96 steps x (L0, L1); y via atomics into yfull[2][BB] ----
  for (int t = 0; t < PP; ++t) {
    {  // dec L0
      f32x4 R = z4, Z = z4, NH = z4;
      f32x4 D0 = z4, D1 = z4, D2 = z4;
      pipe_phase<false>(ringfc, h1cH, h1cL, pkD0H + woff, pkD0H + woff,
                        row0w, lane, stg, R, Z, NH, D0, D1, D2);
      float yl[4] = {0, 0, 0, 0};
      if (t > 0) {
        const float* yb = yfull + ((t - 1) & 1) * BB;
#pragma unroll
        for (int r = 0; r < 4; ++r) {
          const float* p = yb + (row0w + quad * 4 + r);
          asm volatile("global_load_dword %0, %1, off sc0 sc1"
                       : "=&v"(yl[r]) : "v"(p) : "memory");
        }
        WAIT_VM(0);
#pragma unroll
        for (int r = 0; r < 4; ++r)
          asm volatile("" : "+v"(yl[r]));
      }
      const float ds0 = dstart[0], ob0 = outb[0];
      const float bir = dbi0[col],          bhr = dbh0[col];
      const float biz = dbi0[HD + col],     bhz = dbh0[HD + col];
      const float bin = dbi0[2 * HD + col], bhn = dbh0[2 * HD + col];
      const float w0r = dW0[col], w0z = dW0[HD + col], w0n = dW0[2 * HD + col];
#pragma unroll
      for (int r = 0; r < 4; ++r) {
        const int row = row0w + quad * 4 + r;
        const size_t idx = (size_t)row * HD + col;
        float yv = (t == 0) ? ds0 : (ob0 + yl[r]);
        if (t > 0 && jb == 0 && fc == 0 && n16 == 0)
          dout[(size_t)row * PP + (t - 1)] = yv;
        float rr = sigm(R[r] + bir + bhr + yv * w0r);
        float zz = sigm(Z[r] + biz + bhz + yv * w0z);
        float nn = tanh_(bin + yv * w0n + rr * (NH[r] + bhn));
        float hv = (1.f - zz) * nn + zz * ht1[r];
        ht1[r] = hv;
        store_h_sc(h1nH, h1nL, idx, hv);
      }
    }
    gbar(geng, GRPB * (++it));
    {  // dec L1: x-phase (d1 new) + h-phase (d2); y partials via atomicAdd
      f32x4 R = z4, Z = z4, NX = z4, NH = z4;
      f32x4 D0 = z4, D1 = z4, D2 = z4;
      pipe_phase<false>(ringfc, h1nH, h1nL, pkD1I + woff, pkD1I + woff,
                        row0w, lane, stg, R, Z, NX, D0, D1, D2);
      pipe_phase<false>(ringfc, h2cH, h2cL, pkD1H + woff, pkD1H + woff,
                        row0w, lane, stg, R, Z, NH, D0, D1, D2);
      const float bir = dbi1[col],          bhr = dbh1[col];
      const float biz = dbi1[HD + col],     bhz = dbh1[HD + col];
      const float bin = dbi1[2 * HD + col], bhn = dbh1[2 * HD + col];
      const float wo = outW[col];
      float* yw = yfull + (t & 1) * BB;
      float* yz = yfull + ((t - 1) & 1) * BB;
#pragma unroll
      for (int r = 0; r < 4; ++r) {
        const int row = row0w + quad * 4 + r;
        const size_t idx = (size_t)row * HD + col;
        float rr = sigm(R[r] + bir + bhr);
        float zz = sigm(Z[r] + biz + bhz);
        float nn = tanh_(NX[r] + bin + rr * (NH[r] + bhn));
        float hv = (1.f - zz) * nn + zz * ht2[r];
        ht2[r] = hv;
        store_h_sc(h2nH, h2nL, idx, hv);
        float v = hv * wo;
#pragma unroll
        for (int off = 1; off < 16; off <<= 1) v += __shfl_xor(v, off, 16);
        if (n16 == 0) {
          atomicAdd(yw + row, v);
          // zero last parity (read by dec L0 this iter; rewritten at t+1)
          if (t > 0 && jb == 0 && fc == 0) store_sc_f32(yz + row, 0.f);
        }
      }
    }
    gbar(geng, GRPB * (++it));
    { u16* t0 = h1cH; h1cH = h1nH; h1nH = t0;
      u16* t1 = h1cL; h1cL = h1nL; h1nL = t1; }
    { u16* t0 = h2cH; h2cH = h2nH; h2nH = t0;
      u16* t1 = h2cL; h2cL = h2nL; h2nL = t1; }
  }

  // ---- finalize: y(P-1), group-local (each group's jb==0 block owns its
  // 64 rows; last gbar guarantees peer atomicAdds are visible) ----
  if ((b & 15) == 0 && tid < 64) {
    int row = row0 + tid;
    float v = load_sc_f32w(yfull + ((PP - 1) & 1) * BB + row);
    dout[(size_t)row * PP + (PP - 1)] = outb[0] + v;
  }
}

extern "C" void kernel_launch(void* const* d_in, const int* in_sizes, int n_in,
                              void* d_out, int out_size, void* d_ws, size_t ws_size,
                              hipStream_t stream) {
  const float* x      = (const float*)d_in[0];
  const float* eW_ih0 = (const float*)d_in[1];
  const float* eW_hh0 = (const float*)d_in[2];
  const float* eb_ih0 = (const float*)d_in[3];
  const float* eb_hh0 = (const float*)d_in[4];
  const float* eW_ih1 = (const float*)d_in[5];
  const float* eW_hh1 = (const float*)d_in[6];
  const float* eb_ih1 = (const float*)d_in[7];
  const float* eb_hh1 = (const float*)d_in[8];
  const float* dW_ih0 = (const float*)d_in[9];
  const float* dW_hh0 = (const float*)d_in[10];
  const float* db_ih0 = (const float*)d_in[11];
  const float* db_hh0 = (const float*)d_in[12];
  const float* dW_ih1 = (const float*)d_in[13];
  const float* dW_hh1 = (const float*)d_in[14];
  const float* db_ih1 = (const float*)d_in[15];
  const float* db_hh1 = (const float*)d_in[16];
  const float* outW   = (const float*)d_in[17];
  const float* outb   = (const float*)d_in[18];
  const float* dstart = (const float*)d_in[19];
  float* out = (float*)d_out;

  char* w = (char*)d_ws;
  size_t off = 0;
  auto carve = [&](size_t bytes) -> void* {
    void* p = w + off;
    off = (off + bytes + 255) & ~(size_t)255;
    return p;
  };
  u16* h1aH = (u16*)carve((size_t)BB * HD * 2); u16* h1aL = (u16*)carve((size_t)BB * HD * 2);
  u16* h1bH = (u16*)carve((size_t)BB * HD * 2); u16* h1bL = (u16*)carve((size_t)BB * HD * 2);
  u16* h2aH = (u16*)carve((size_t)BB * HD * 2); u16* h2aL = (u16*)carve((size_t)BB * HD * 2);
  u16* h2bH = (u16*)carve((size_t)BB * HD * 2); u16* h2bL = (u16*)carve((size_t)BB * HD * 2);
  float* yfull = (float*)carve((size_t)2 * BB * 4);
  unsigned* gen = (unsigned*)carve(4096);  // 16 group counters, 256-B stride
  auto carve_pack = [&](int K) -> u16* {
    return (u16*)carve((size_t)3 * HD * K * 2 * 2);
  };
  u16* pk_e0ih = carve_pack(DIN);
  u16* pk_e0hh = carve_pack(HD);
  u16* pk_e1ih = carve_pack(HD);
  u16* pk_e1hh = carve_pack(HD);
  u16* pk_d0hh = carve_pack(HD);
  u16* pk_d1ih = carve_pack(HD);
  u16* pk_d1hh = carve_pack(HD);

  hipMemsetAsync(h1aH, 0, (size_t)BB * HD * 2, stream);
  hipMemsetAsync(h1aL, 0, (size_t)BB * HD * 2, stream);
  hipMemsetAsync(h2aH, 0, (size_t)BB * HD * 2, stream);
  hipMemsetAsync(h2aL, 0, (size_t)BB * HD * 2, stream);
  hipMemsetAsync(yfull, 0, (size_t)2 * BB * 4, stream);
  hipMemsetAsync(gen, 0, 4096, stream);

  auto pack = [&](const float* W, int K, u16* dst) {
    int total = 16 * (K >> 5) * 2 * 6 * 64;
    pack_w_kernel<<<(total + 255) / 256, 256, 0, stream>>>(W, K, dst);
  };
  pack(eW_ih0, DIN, pk_e0ih);
  pack(eW_hh0, HD, pk_e0hh);
  pack(eW_ih1, HD, pk_e1ih);
  pack(eW_hh1, HD, pk_e1hh);
  pack(dW_hh0, HD, pk_d0hh);
  pack(dW_ih1, HD, pk_d1ih);
  pack(dW_hh1, HD, pk_d1hh);

  gru_persistent_kernel<<<NBLK, 512, 0, stream>>>(
      x, pk_e0ih, pk_e0hh, eb_ih0, eb_hh0,
      pk_e1ih, pk_e1hh, eb_ih1, eb_hh1,
      pk_d0hh, db_ih0, db_hh0, dW_ih0,
      pk_d1ih, pk_d1hh, db_ih1, db_hh1,
      outW, outb, dstart,
      h1aH, h1aL, h1bH, h1bL, h2aH, h2aL, h2bH, h2bL,
      yfull, out, gen);
}

// Round 4
// 16917.917 us; speedup vs baseline: 1.2301x; 1.1996x over previous
//
#include <hip/hip_runtime.h>

#define HD 512
#define BB 1024
#define TT 512
#define PP 96
#define DIN 32
#define KC_H 16
#define NBLK 256
#define GRPB 16  // blocks per row-group barrier (all 16 jb of one row group)

typedef unsigned short u16;
typedef __attribute__((ext_vector_type(8))) short bf16x8;
typedef __attribute__((ext_vector_type(4))) float f32x4;
typedef __attribute__((address_space(3))) unsigned int lds_u32;
typedef __attribute__((address_space(3))) u16 lds_u16;
typedef __attribute__((address_space(1))) unsigned int glb_u32;

#define WAIT_VM(N) asm volatile("s_waitcnt vmcnt(" #N ")" ::: "memory")
__device__ __forceinline__ void bar_raw() { asm volatile("s_barrier" ::: "memory"); }

__device__ __forceinline__ float bf2f(u16 s) {
  return __uint_as_float(((unsigned)s) << 16);
}
__device__ __forceinline__ u16 f2bf_rne(float f) {
  unsigned u = __float_as_uint(f);
  u += 0x7FFF + ((u >> 16) & 1);
  return (u16)(u >> 16);
}
__device__ __forceinline__ float sigm(float v) { return 1.f / (1.f + __expf(-v)); }
__device__ __forceinline__ float tanh_(float a) {
  return 1.f - 2.f / (__expf(2.f * a) + 1.f);
}

// ---- coherent (L2-bypass) access helpers: sc0 sc1 ----
__device__ __forceinline__ bf16x8 load_sc16(const u16* p) {
  bf16x8 r;
  asm volatile("global_load_dwordx4 %0, %1, off sc0 sc1" : "=&v"(r) : "v"(p) : "memory");
  return r;
}
__device__ __forceinline__ void store_sc_u16(u16* p, unsigned v) {
  asm volatile("global_store_short %0, %1, off sc0 sc1" :: "v"(p), "v"(v) : "memory");
}
__device__ __forceinline__ void store_sc_f32(float* p, float v) {
  asm volatile("global_store_dword %0, %1, off sc0 sc1" :: "v"(p), "v"(v) : "memory");
}
__device__ __forceinline__ float load_sc_f32w(const float* p) {  // load + full wait
  float v;
  asm volatile("global_load_dword %0, %1, off sc0 sc1\ns_waitcnt vmcnt(0)"
               : "=&v"(v) : "v"(p) : "memory");
  return v;
}
__device__ __forceinline__ unsigned load_sc_u32w(const unsigned* p) {
  unsigned v;
  asm volatile("global_load_dword %0, %1, off sc0 sc1\ns_waitcnt vmcnt(0)"
               : "=&v"(v) : "v"(p) : "memory");
  return v;
}
__device__ __forceinline__ void store_h_sc(u16* H, u16* L, size_t idx, float hv) {
  u16 hi = (u16)(__float_as_uint(hv) >> 16);  // trunc; lo corrects
  u16 lo = f2bf_rne(hv - bf2f(hi));
  store_sc_u16(H + idx, (unsigned)hi);
  store_sc_u16(L + idx, (unsigned)lo);
}

// Pack fp32 weight W[3H x K] into fc-contiguous MFMA B-frag bf16 hi/lo layout:
// group512 = ((jb*KC + kc)*2 + fc)*6 + (g*2 + s);  u16 off = group*512 + lane*8
__global__ void pack_w_kernel(const float* __restrict__ W, int K,
                              u16* __restrict__ out) {
  int tid = blockIdx.x * 256 + threadIdx.x;
  int KC = K >> 5;
  int total = 16 * KC * 2 * 6 * 64;
  if (tid >= total) return;
  int lane = tid & 63;
  int rest = tid >> 6;
  int gs = rest % 6; rest /= 6;
  int fc = rest & 1; rest >>= 1;
  int kc = rest % KC;
  int jb = rest / KC;
  int g = gs >> 1, s = gs & 1;
  int j = jb * 32 + fc * 16 + (lane & 15);
  int k = kc * 32 + (lane >> 4) * 8;
  const float* src = W + (size_t)(g * HD + j) * K + k;
  bf16x8 v;
#pragma unroll
  for (int i = 0; i < 8; ++i) {
    float f = src[i];
    u16 hi = f2bf_rne(f);
    v[i] = (short)((s == 0) ? hi : f2bf_rne(f - bf2f(hi)));
  }
  *(bf16x8*)(out + (size_t)tid * 8) = v;
}

// 4-wave layout: wave = rowg (16 rows), each wave computes BOTH fc column
// halves (32 cols) -> A-fragment loaded ONCE per 16 rows (halves LLC A-read
// stream vs the fc-split layout; fc-pair duplication eliminated).
struct AF { bf16x8 h; bf16x8 l; };

__device__ __forceinline__ void fence_af(AF& a) {
  asm volatile("" : "+v"(a.h), "+v"(a.l));
}
// 2 sc1 loads, exact issue order (volatile) for vmcnt accounting.
__device__ __forceinline__ void load_af_sc(AF& a, const u16* aH0, const u16* aL0, int kc) {
  a.h = load_sc16(aH0 + kc * 32);
  a.l = load_sc16(aL0 + kc * 32);
}

// 9 MFMAs for one kc from an LDS chunk (3072 u16: (g*2+s)*512 + lane*8).
__device__ __forceinline__ void mfma_kc_l(const lds_u16* base, int lane, const AF& a,
                                          f32x4& aR, f32x4& aZ, f32x4& aN) {
  typedef __attribute__((address_space(3))) const bf16x8 lds_bf16x8;
  const lds_u16* p = base + lane * 8;
#pragma unroll
  for (int g = 0; g < 3; ++g) {
    f32x4* acc = (g == 0) ? &aR : (g == 1) ? &aZ : &aN;
    bf16x8 whi = *(lds_bf16x8*)(p + (g * 2 + 0) * 512);
    bf16x8 wlo = *(lds_bf16x8*)(p + (g * 2 + 1) * 512);
    *acc = __builtin_amdgcn_mfma_f32_16x16x32_bf16(a.h, whi, *acc, 0, 0, 0);
    *acc = __builtin_amdgcn_mfma_f32_16x16x32_bf16(a.l, whi, *acc, 0, 0, 0);
    *acc = __builtin_amdgcn_mfma_f32_16x16x32_bf16(a.h, wlo, *acc, 0, 0, 0);
  }
}
// Same from global (x-phase weights, L2-hot, compiler-managed waits).
__device__ __forceinline__ void mfma_kc_g(const u16* base, int lane, const AF& a,
                                          f32x4& aR, f32x4& aZ, f32x4& aN) {
  const u16* p = base + lane * 8;
#pragma unroll
  for (int g = 0; g < 3; ++g) {
    f32x4* acc = (g == 0) ? &aR : (g == 1) ? &aZ : &aN;
    bf16x8 whi = *(const bf16x8*)(p + (g * 2 + 0) * 512);
    bf16x8 wlo = *(const bf16x8*)(p + (g * 2 + 1) * 512);
    *acc = __builtin_amdgcn_mfma_f32_16x16x32_bf16(a.h, whi, *acc, 0, 0, 0);
    *acc = __builtin_amdgcn_mfma_f32_16x16x32_bf16(a.l, whi, *acc, 0, 0, 0);
    *acc = __builtin_amdgcn_mfma_f32_16x16x32_bf16(a.h, wlo, *acc, 0, 0, 0);
  }
}

// 6 x 1KB LDS-DMA of one 6KB weight chunk (normal cached reads -> L2-hot).
__device__ __forceinline__ void stage6(const u16* src, u16* dst, int lane) {
#pragma unroll
  for (int j = 0; j < 6; ++j)
    __builtin_amdgcn_global_load_lds((const glb_u32*)(src + j * 512 + lane * 8),
                                     (lds_u32*)(dst + j * 512), 16, 0, 0);
}

// K=512 GEMM phase. 4-slot LDS ring (slot = 24KB: fc0{A|B} fc1{A|B}),
// prologue 3, lead 3. Stagers = waves 0,1 (fc 0,1): bundle = 12(DUAL)/6
// W-DMAs + 2 A-loads; consumers: 2 A-loads. All waves consume both fc.
// Raw s_barrier handoff; manual vmcnt; no __syncthreads, no fences.
template <bool DUAL>
__device__ __forceinline__ void pipe_phase(
    u16* ringb, const u16* Ahi, const u16* Alo,
    const u16* WA, const u16* WB, int row0w, int lane, bool stg, int sfc,
    f32x4* aR, f32x4* aZ, f32x4* aN,
    f32x4* bR, f32x4* bZ, f32x4* bN) {
  const int quad = lane >> 4, n16 = lane & 15;
  const u16* aH0 = Ahi + (size_t)(row0w + n16) * HD + quad * 8;
  const u16* aL0 = Alo + (size_t)(row0w + n16) * HD + quad * 8;
  u16* pb[4] = {ringb, ringb + 12288, ringb + 2 * 12288, ringb + 3 * 12288};
  AF a0, a1, a2, a3;

  auto issueB = [&](int ikc, u16* slot, AF& dst) {
    if (stg) {
      stage6(WA + (size_t)ikc * 6144, slot + sfc * 6144, lane);
      if constexpr (DUAL) stage6(WB + (size_t)ikc * 6144, slot + sfc * 6144 + 3072, lane);
    }
    load_af_sc(dst, aH0, aL0, ikc);
  };
  auto cons = [&](u16* slot, AF& a) {
    fence_af(a);
#pragma unroll
    for (int f = 0; f < 2; ++f) {
      mfma_kc_l((const lds_u16*)(slot + f * 6144), lane, a, aR[f], aZ[f], aN[f]);
      if constexpr (DUAL)
        mfma_kc_l((const lds_u16*)(slot + f * 6144 + 3072), lane, a, bR[f], bZ[f], bN[f]);
    }
  };
  auto wsteady = [&]() {  // oldest of 3 bundles done -> 2 bundles outstanding
    if (stg) { if constexpr (DUAL) WAIT_VM(28); else WAIT_VM(16); }
    else WAIT_VM(4);
  };
  auto wtail1 = [&]() {  // 1 bundle outstanding
    if (stg) { if constexpr (DUAL) WAIT_VM(14); else WAIT_VM(8); }
    else WAIT_VM(2);
  };

  WAIT_VM(0);  // drain unrelated vm-ops so bundle counting is exact
  issueB(0, pb[0], a0);
  issueB(1, pb[1], a1);
  issueB(2, pb[2], a2);
#pragma unroll 1
  for (int kc = 0; kc < 12; kc += 4) {
    wsteady(); bar_raw(); issueB(kc + 3, pb[3], a3); cons(pb[0], a0);
    wsteady(); bar_raw(); issueB(kc + 4, pb[0], a0); cons(pb[1], a1);
    wsteady(); bar_raw(); issueB(kc + 5, pb[1], a1); cons(pb[2], a2);
    wsteady(); bar_raw(); issueB(kc + 6, pb[2], a2); cons(pb[3], a3);
  }
  wsteady(); bar_raw(); issueB(15, pb[3], a3); cons(pb[0], a0);  // kc=12
  wsteady(); bar_raw(); cons(pb[1], a1);                         // kc=13
  wtail1();  bar_raw(); cons(pb[2], a2);                         // kc=14
  WAIT_VM(0); bar_raw(); cons(pb[3], a3);                        // kc=15
}

// x-phase for encoder L0: fp32 x[B,T,32], K=32, weights/x normal (L2-hot).
// One 16-row A-fragment feeds both fc weight chunks.
__device__ __forceinline__ void x_phase(const float* x, int t, const u16* Wp,
                                        int jb, int row0w, int lane,
                                        f32x4* aR, f32x4* aZ, f32x4* aN) {
  const int quad = lane >> 4, n16 = lane & 15;
  AF ax;
  const float* xp = x + (size_t)(row0w + n16) * (TT * DIN) +
                    (size_t)t * DIN + quad * 8;
  f32x4 v0 = *(const f32x4*)xp;
  f32x4 v1 = *(const f32x4*)(xp + 4);
  bf16x8 hi, lo;
#pragma unroll
  for (int i = 0; i < 8; ++i) {
    float f = (i < 4) ? v0[i] : v1[i - 4];
    u16 h = (u16)(__float_as_uint(f) >> 16);
    hi[i] = (short)h;
    lo[i] = (short)f2bf_rne(f - bf2f(h));
  }
  ax.h = hi;
  ax.l = lo;
#pragma unroll
  for (int f = 0; f < 2; ++f)
    mfma_kc_g(Wp + ((size_t)jb * 2 + f) * 3072, lane, ax, aR[f], aZ[f], aN[f]);
}

// Row-group barrier (16 blocks sharing row0): every cross-block dependency in
// this kernel is row-preserving, so a 16-block barrier on a private counter
// line suffices. No cache invalidation: sc1 traffic already coherent.
__device__ __forceinline__ void gbar(unsigned* gen, unsigned target) {
  WAIT_VM(0);  // all this wave's sc1 stores / atomics globally visible
  __syncthreads();
  if (threadIdx.x == 0) {
    atomicAdd(gen, 1u);  // device-scope by default
    while (load_sc_u32w(gen) < target) __builtin_amdgcn_s_sleep(2);
  }
  __syncthreads();
}

// GRU epilogue with register-resident own-tile h (ho never re-read from mem).
__device__ __forceinline__ void gru_epi_reg(
    const float* bi, const float* bh, float (*ht)[4],
    u16* hnH, u16* hnL, int col0, int row0w, int quad,
    const f32x4* aR, const f32x4* aZ, const f32x4* aNX, const f32x4* aNH) {
#pragma unroll
  for (int f = 0; f < 2; ++f) {
    const int col = col0 + f * 16;
    const float bir = bi[col],          bhr = bh[col];
    const float biz = bi[HD + col],     bhz = bh[HD + col];
    const float bin = bi[2 * HD + col], bhn = bh[2 * HD + col];
#pragma unroll
    for (int r = 0; r < 4; ++r) {
      const int row = row0w + quad * 4 + r;
      const size_t idx = (size_t)row * HD + col;
      float rr = sigm(aR[f][r] + bir + bhr);
      float zz = sigm(aZ[f][r] + biz + bhz);
      float nn = tanh_(aNX[f][r] + bin + rr * (aNH[f][r] + bhn));
      float hv = (1.f - zz) * nn + zz * ht[f][r];
      ht[f][r] = hv;
      store_h_sc(hnH, hnL, idx, hv);
    }
  }
}

__global__ __launch_bounds__(256, 1)
void gru_persistent_kernel(
    const float* x,
    const u16* pkX0, const u16* pkH0, const float* bi0, const float* bh0,
    const u16* pkX1, const u16* pkH1, const float* bi1, const float* bh1,
    const u16* pkD0H, const float* dbi0, const float* dbh0, const float* dW0,
    const u16* pkD1I, const u16* pkD1H, const float* dbi1, const float* dbh1,
    const float* outW, const float* outb, const float* dstart,
    u16* h1aH, u16* h1aL, u16* h1bH, u16* h1bL,
    u16* h2aH, u16* h2aL, u16* h2bH, u16* h2bL,
    float* yfull, float* dout, unsigned* gen) {
  __shared__ u16 ring[4][12288];  // 96 KB: unified 4-slot weight ring
  const int b = blockIdx.x;
  const int jb = (b & 7) * 2 + ((b >> 3) & 1);  // XCD-local jb
  const int row0 = (b >> 4) * 64;
  const int tid = threadIdx.x, wave = tid >> 6, lane = tid & 63;
  const int quad = lane >> 4, n16 = lane & 15;
  const bool stg = (wave < 2);
  const int sfc = wave & 1;          // stager wave w stages fc=w
  const int row0w = row0 + wave * 16;  // 4 waves = 4 row groups
  const int col0 = jb * 32 + n16;
  u16* ringb = &ring[0][0];
  const f32x4 z4 = {0.f, 0.f, 0.f, 0.f};
  const size_t woffw = ((size_t)jb * KC_H * 2 + sfc) * 3072;  // kc stride 6144
  // Per-row-group barrier counter: one u32 per group, 256-B line separation.
  unsigned* geng = gen + ((b >> 4) << 6);

  u16 *h1cH = h1aH, *h1cL = h1aL, *h1nH = h1bH, *h1nL = h1bL;
  u16 *h2cH = h2aH, *h2cL = h2aL, *h2nH = h2bH, *h2nL = h2bL;
  float ht1[2][4] = {{0, 0, 0, 0}, {0, 0, 0, 0}};  // own h1 tile (fc, r)
  float ht2[2][4] = {{0, 0, 0, 0}, {0, 0, 0, 0}};  // own h2 tile (fc, r)
  unsigned it = 0;

  // ---- encoder: 513 skewed phases; fused h1c stream feeds L0-h AND L1-x ----
  for (int k = 0; k <= TT; ++k) {
    f32x4 R0[2] = {z4, z4}, Z0[2] = {z4, z4}, NX0[2] = {z4, z4}, NH0[2] = {z4, z4};
    f32x4 R1[2] = {z4, z4}, Z1[2] = {z4, z4}, NX1[2] = {z4, z4}, NH1[2] = {z4, z4};
    if (k > 0 && k < TT) {
      pipe_phase<true>(ringb, h1cH, h1cL, pkH0 + woffw, pkX1 + woffw,
                       row0w, lane, stg, sfc, R0, Z0, NH0, R1, Z1, NX1);
    } else if (k == 0) {
      pipe_phase<false>(ringb, h1cH, h1cL, pkH0 + woffw, pkH0 + woffw,
                        row0w, lane, stg, sfc, R0, Z0, NH0, R1, Z1, NX1);
    } else {  // k == TT
      pipe_phase<false>(ringb, h1cH, h1cL, pkX1 + woffw, pkX1 + woffw,
                        row0w, lane, stg, sfc, R1, Z1, NX1, R0, Z0, NH0);
    }
    if (k < TT) {
      x_phase(x, k, pkX0, jb, row0w, lane, R0, Z0, NX0);
      gru_epi_reg(bi0, bh0, ht1, h1nH, h1nL, col0, row0w, quad, R0, Z0, NX0, NH0);
    }
    if (k > 0) {
      pipe_phase<false>(ringb, h2cH, h2cL, pkH1 + woffw, pkH1 + woffw,
                        row0w, lane, stg, sfc, R1, Z1, NH1, R0, Z0, NX0);
      gru_epi_reg(bi1, bh1, ht2, h2nH, h2nL, col0, row0w, quad, R1, Z1, NX1, NH1);
    }
    gbar(geng, GRPB * (++it));
    if (k < TT) { u16* t0 = h1cH; h1cH = h1nH; h1nH = t0;
                  u16* t1 = h1cL; h1cL = h1nL; h1nL = t1; }
    if (k > 0)  { u16* t0 = h2cH; h2cH = h2nH; h2nH = t0;
                  u16* t1 = h2cL; h2cL = h2nL; h2nL = t1; }
  }

  // ---- decoder: 96 steps x (L0, L1); y via atomics into yfull[2][BB] ----
  for (int t = 0; t < PP; ++t) {
    {  // dec L0
      f32x4 R[2] = {z4, z4}, Z[2] = {z4, z4}, NH[2] = {z4, z4};
      f32x4 D0[2] = {z4, z4}, D1[2] = {z4, z4}, D2[2] = {z4, z4};
      pipe_phase<false>(ringb, h1cH, h1cL, pkD0H + woffw, pkD0H + woffw,
                        row0w, lane, stg, sfc, R, Z, NH, D0, D1, D2);
      float yl[4] = {0, 0, 0, 0};
      if (t > 0) {
        const float* yb = yfull + ((t - 1) & 1) * BB;
#pragma unroll
        for (int r = 0; r < 4; ++r) {
          const float* p = yb + (row0w + quad * 4 + r);
          asm volatile("global_load_dword %0, %1, off sc0 sc1"
                       : "=&v"(yl[r]) : "v"(p) : "memory");
        }
        WAIT_VM(0);
#pragma unroll
        for (int r = 0; r < 4; ++r)
          asm volatile("" : "+v"(yl[r]));
      }
      const float ds0 = dstart[0], ob0 = outb[0];
#pragma unroll
      for (int f = 0; f < 2; ++f) {
        const int col = col0 + f * 16;
        const float bir = dbi0[col],          bhr = dbh0[col];
        const float biz = dbi0[HD + col],     bhz = dbh0[HD + col];
        const float bin = dbi0[2 * HD + col], bhn = dbh0[2 * HD + col];
        const float w0r = dW0[col], w0z = dW0[HD + col], w0n = dW0[2 * HD + col];
#pragma unroll
        for (int r = 0; r < 4; ++r) {
          const int row = row0w + quad * 4 + r;
          const size_t idx = (size_t)row * HD + col;
          float yv = (t == 0) ? ds0 : (ob0 + yl[r]);
          if (f == 0 && t > 0 && jb == 0 && n16 == 0)
            dout[(size_t)row * PP + (t - 1)] = yv;
          float rr = sigm(R[f][r] + bir + bhr + yv * w0r);
          float zz = sigm(Z[f][r] + biz + bhz + yv * w0z);
          float nn = tanh_(bin + yv * w0n + rr * (NH[f][r] + bhn));
          float hv = (1.f - zz) * nn + zz * ht1[f][r];
          ht1[f][r] = hv;
          store_h_sc(h1nH, h1nL, idx, hv);
        }
      }
    }
    gbar(geng, GRPB * (++it));
    {  // dec L1: x-phase (d1 new) + h-phase (d2); y partials via atomicAdd
      f32x4 R[2] = {z4, z4}, Z[2] = {z4, z4}, NX[2] = {z4, z4}, NH[2] = {z4, z4};
      f32x4 D0[2] = {z4, z4}, D1[2] = {z4, z4}, D2[2] = {z4, z4};
      pipe_phase<false>(ringb, h1nH, h1nL, pkD1I + woffw, pkD1I + woffw,
                        row0w, lane, stg, sfc, R, Z, NX, D0, D1, D2);
      pipe_phase<false>(ringb, h2cH, h2cL, pkD1H + woffw, pkD1H + woffw,
                        row0w, lane, stg, sfc, R, Z, NH, D0, D1, D2);
      float vs[4] = {0, 0, 0, 0};
#pragma unroll
      for (int f = 0; f < 2; ++f) {
        const int col = col0 + f * 16;
        const float bir = dbi1[col],          bhr = dbh1[col];
        const float biz = dbi1[HD + col],     bhz = dbh1[HD + col];
        const float bin = dbi1[2 * HD + col], bhn = dbh1[2 * HD + col];
        const float wo = outW[col];
#pragma unroll
        for (int r = 0; r < 4; ++r) {
          const int row = row0w + quad * 4 + r;
          const size_t idx = (size_t)row * HD + col;
          float rr = sigm(R[f][r] + bir + bhr);
          float zz = sigm(Z[f][r] + biz + bhz);
          float nn = tanh_(NX[f][r] + bin + rr * (NH[f][r] + bhn));
          float hv = (1.f - zz) * nn + zz * ht2[f][r];
          ht2[f][r] = hv;
          store_h_sc(h2nH, h2nL, idx, hv);
          float v = hv * wo;
#pragma unroll
          for (int off = 1; off < 16; off <<= 1) v += __shfl_xor(v, off, 16);
          vs[r] += v;
        }
      }
      float* yw = yfull + (t & 1) * BB;
      float* yz = yfull + ((t - 1) & 1) * BB;
#pragma unroll
      for (int r = 0; r < 4; ++r) {
        const int row = row0w + quad * 4 + r;
        if (n16 == 0) {
          atomicAdd(yw + row, vs[r]);
          // zero last parity (read by dec L0 this iter; rewritten at t+1)
          if (t > 0 && jb == 0) store_sc_f32(yz + row, 0.f);
        }
      }
    }
    gbar(geng, GRPB * (++it));
    { u16* t0 = h1cH; h1cH = h1nH; h1nH = t0;
      u16* t1 = h1cL; h1cL = h1nL; h1nL = t1; }
    { u16* t0 = h2cH; h2cH = h2nH; h2nH = t0;
      u16* t1 = h2cL; h2cL = h2nL; h2nL = t1; }
  }

  // ---- finalize: y(P-1), group-local (each group's jb==0 block owns its
  // 64 rows; last gbar guarantees peer atomicAdds are visible) ----
  if ((b & 15) == 0 && tid < 64) {
    int row = row0 + tid;
    float v = load_sc_f32w(yfull + ((PP - 1) & 1) * BB + row);
    dout[(size_t)row * PP + (PP - 1)] = outb[0] + v;
  }
}

extern "C" void kernel_launch(void* const* d_in, const int* in_sizes, int n_in,
                              void* d_out, int out_size, void* d_ws, size_t ws_size,
                              hipStream_t stream) {
  const float* x      = (const float*)d_in[0];
  const float* eW_ih0 = (const float*)d_in[1];
  const float* eW_hh0 = (const float*)d_in[2];
  const float* eb_ih0 = (const float*)d_in[3];
  const float* eb_hh0 = (const float*)d_in[4];
  const float* eW_ih1 = (const float*)d_in[5];
  const float* eW_hh1 = (const float*)d_in[6];
  const float* eb_ih1 = (const float*)d_in[7];
  const float* eb_hh1 = (const float*)d_in[8];
  const float* dW_ih0 = (const float*)d_in[9];
  const float* dW_hh0 = (const float*)d_in[10];
  const float* db_ih0 = (const float*)d_in[11];
  const float* db_hh0 = (const float*)d_in[12];
  const float* dW_ih1 = (const float*)d_in[13];
  const float* dW_hh1 = (const float*)d_in[14];
  const float* db_ih1 = (const float*)d_in[15];
  const float* db_hh1 = (const float*)d_in[16];
  const float* outW   = (const float*)d_in[17];
  const float* outb   = (const float*)d_in[18];
  const float* dstart = (const float*)d_in[19];
  float* out = (float*)d_out;

  char* w = (char*)d_ws;
  size_t off = 0;
  auto carve = [&](size_t bytes) -> void* {
    void* p = w + off;
    off = (off + bytes + 255) & ~(size_t)255;
    return p;
  };
  u16* h1aH = (u16*)carve((size_t)BB * HD * 2); u16* h1aL = (u16*)carve((size_t)BB * HD * 2);
  u16* h1bH = (u16*)carve((size_t)BB * HD * 2); u16* h1bL = (u16*)carve((size_t)BB * HD * 2);
  u16* h2aH = (u16*)carve((size_t)BB * HD * 2); u16* h2aL = (u16*)carve((size_t)BB * HD * 2);
  u16* h2bH = (u16*)carve((size_t)BB * HD * 2); u16* h2bL = (u16*)carve((size_t)BB * HD * 2);
  float* yfull = (float*)carve((size_t)2 * BB * 4);
  unsigned* gen = (unsigned*)carve(4096);  // 16 group counters, 256-B stride
  auto carve_pack = [&](int K) -> u16* {
    return (u16*)carve((size_t)3 * HD * K * 2 * 2);
  };
  u16* pk_e0ih = carve_pack(DIN);
  u16* pk_e0hh = carve_pack(HD);
  u16* pk_e1ih = carve_pack(HD);
  u16* pk_e1hh = carve_pack(HD);
  u16* pk_d0hh = carve_pack(HD);
  u16* pk_d1ih = carve_pack(HD);
  u16* pk_d1hh = carve_pack(HD);

  hipMemsetAsync(h1aH, 0, (size_t)BB * HD * 2, stream);
  hipMemsetAsync(h1aL, 0, (size_t)BB * HD * 2, stream);
  hipMemsetAsync(h2aH, 0, (size_t)BB * HD * 2, stream);
  hipMemsetAsync(h2aL, 0, (size_t)BB * HD * 2, stream);
  hipMemsetAsync(yfull, 0, (size_t)2 * BB * 4, stream);
  hipMemsetAsync(gen, 0, 4096, stream);

  auto pack = [&](const float* W, int K, u16* dst) {
    int total = 16 * (K >> 5) * 2 * 6 * 64;
    pack_w_kernel<<<(total + 255) / 256, 256, 0, stream>>>(W, K, dst);
  };
  pack(eW_ih0, DIN, pk_e0ih);
  pack(eW_hh0, HD, pk_e0hh);
  pack(eW_ih1, HD, pk_e1ih);
  pack(eW_hh1, HD, pk_e1hh);
  pack(dW_hh0, HD, pk_d0hh);
  pack(dW_ih1, HD, pk_d1ih);
  pack(dW_hh1, HD, pk_d1hh);

  gru_persistent_kernel<<<NBLK, 256, 0, stream>>>(
      x, pk_e0ih, pk_e0hh, eb_ih0, eb_hh0,
      pk_e1ih, pk_e1hh, eb_ih1, eb_hh1,
      pk_d0hh, db_ih0, db_hh0, dW_ih0,
      pk_d1ih, pk_d1hh, db_ih1, db_hh1,
      outW, outb, dstart,
      h1aH, h1aL, h1bH, h1bL, h2aH, h2aL, h2bH, h2bL,
      yfull, out, gen);
}

// Round 5
// 16268.573 us; speedup vs baseline: 1.2792x; 1.0399x over previous
//
#include <hip/hip_runtime.h>

#define HD 512
#define BB 1024
#define TT 512
#define PP 96
#define DIN 32
#define KC_H 16
#define NBLK 256
#define GRPB 16  // blocks per row-group barrier (all 16 jb of one row group)

typedef unsigned short u16;
typedef __attribute__((ext_vector_type(8))) short bf16x8;
typedef __attribute__((ext_vector_type(4))) float f32x4;
typedef __attribute__((address_space(3))) unsigned int lds_u32;
typedef __attribute__((address_space(3))) u16 lds_u16;
typedef __attribute__((address_space(1))) unsigned int glb_u32;

#define WAIT_VM(N) asm volatile("s_waitcnt vmcnt(" #N ")" ::: "memory")
__device__ __forceinline__ void bar_raw() { asm volatile("s_barrier" ::: "memory"); }

template <int N> __device__ __forceinline__ void wvm() {
  if constexpr (N == 0) WAIT_VM(0);
  else if constexpr (N == 5) WAIT_VM(5);
  else if constexpr (N == 10) WAIT_VM(10);
  else if constexpr (N == 13) WAIT_VM(13);
  else if constexpr (N == 20) WAIT_VM(20);
  else if constexpr (N == 26) WAIT_VM(26);
}

__device__ __forceinline__ float bf2f(u16 s) {
  return __uint_as_float(((unsigned)s) << 16);
}
__device__ __forceinline__ u16 f2bf_rne(float f) {
  unsigned u = __float_as_uint(f);
  u += 0x7FFF + ((u >> 16) & 1);
  return (u16)(u >> 16);
}
__device__ __forceinline__ float sigm(float v) { return 1.f / (1.f + __expf(-v)); }
__device__ __forceinline__ float tanh_(float a) {
  return 1.f - 2.f / (__expf(2.f * a) + 1.f);
}

// ---- coherent (L2-bypass) access helpers: sc0 sc1 ----
__device__ __forceinline__ bf16x8 load_sc16(const u16* p) {
  bf16x8 r;
  asm volatile("global_load_dwordx4 %0, %1, off sc0 sc1" : "=&v"(r) : "v"(p) : "memory");
  return r;
}
__device__ __forceinline__ void store_sc_u16(u16* p, unsigned v) {
  asm volatile("global_store_short %0, %1, off sc0 sc1" :: "v"(p), "v"(v) : "memory");
}
__device__ __forceinline__ void store_sc_f32(float* p, float v) {
  asm volatile("global_store_dword %0, %1, off sc0 sc1" :: "v"(p), "v"(v) : "memory");
}
__device__ __forceinline__ float load_sc_f32w(const float* p) {  // load + full wait
  float v;
  asm volatile("global_load_dword %0, %1, off sc0 sc1\ns_waitcnt vmcnt(0)"
               : "=&v"(v) : "v"(p) : "memory");
  return v;
}
__device__ __forceinline__ unsigned load_sc_u32w(const unsigned* p) {
  unsigned v;
  asm volatile("global_load_dword %0, %1, off sc0 sc1\ns_waitcnt vmcnt(0)"
               : "=&v"(v) : "v"(p) : "memory");
  return v;
}
__device__ __forceinline__ void store_h_sc(u16* H, u16* L, size_t idx, float hv) {
  u16 hi = (u16)(__float_as_uint(hv) >> 16);  // trunc; lo corrects
  u16 lo = f2bf_rne(hv - bf2f(hi));
  store_sc_u16(H + idx, (unsigned)hi);
  store_sc_u16(L + idx, (unsigned)lo);
}

// Pack fp32 weight W[3H x K] into fc-contiguous MFMA B-frag bf16 hi/lo layout:
// group512 = ((jb*KC + kc)*2 + fc)*6 + (g*2 + s);  u16 off = group*512 + lane*8
__global__ void pack_w_kernel(const float* __restrict__ W, int K,
                              u16* __restrict__ out) {
  int tid = blockIdx.x * 256 + threadIdx.x;
  int KC = K >> 5;
  int total = 16 * KC * 2 * 6 * 64;
  if (tid >= total) return;
  int lane = tid & 63;
  int rest = tid >> 6;
  int gs = rest % 6; rest /= 6;
  int fc = rest & 1; rest >>= 1;
  int kc = rest % KC;
  int jb = rest / KC;
  int g = gs >> 1, s = gs & 1;
  int j = jb * 32 + fc * 16 + (lane & 15);
  int k = kc * 32 + (lane >> 4) * 8;
  const float* src = W + (size_t)(g * HD + j) * K + k;
  bf16x8 v;
#pragma unroll
  for (int i = 0; i < 8; ++i) {
    float f = src[i];
    u16 hi = f2bf_rne(f);
    v[i] = (short)((s == 0) ? hi : f2bf_rne(f - bf2f(hi)));
  }
  *(bf16x8*)(out + (size_t)tid * 8) = v;
}

// A fragments for NA distinct A-streams (hi/lo split bf16).
template <int NA> struct AFN { bf16x8 h[NA]; bf16x8 l[NA]; };
template <int NA>
__device__ __forceinline__ void fence_afn(AFN<NA>& a) {
#pragma unroll
  for (int n = 0; n < NA; ++n)
    asm volatile("" : "+v"(a.h[n]), "+v"(a.l[n]));
}

// 9 MFMAs for one (stream, fc) 6KB chunk (6 frag groups of 512 u16).
__device__ __forceinline__ void mfma_kc9(const lds_u16* base, int lane,
                                         bf16x8 ah, bf16x8 al,
                                         f32x4& R, f32x4& Z, f32x4& N) {
  typedef __attribute__((address_space(3))) const bf16x8 lds_bf16x8;
  const lds_u16* p = base + lane * 8;
#pragma unroll
  for (int g = 0; g < 3; ++g) {
    f32x4* a = (g == 0) ? &R : (g == 1) ? &Z : &N;
    bf16x8 whi = *(lds_bf16x8*)(p + (g * 2 + 0) * 512);
    bf16x8 wlo = *(lds_bf16x8*)(p + (g * 2 + 1) * 512);
    *a = __builtin_amdgcn_mfma_f32_16x16x32_bf16(ah, whi, *a, 0, 0, 0);
    *a = __builtin_amdgcn_mfma_f32_16x16x32_bf16(al, whi, *a, 0, 0, 0);
    *a = __builtin_amdgcn_mfma_f32_16x16x32_bf16(ah, wlo, *a, 0, 0, 0);
  }
}
// Global variant for the K=32 x-phase (L2-hot, compiler-managed waits).
__device__ __forceinline__ void mfma_kc9_g(const u16* base, int lane,
                                           bf16x8 ah, bf16x8 al,
                                           f32x4& R, f32x4& Z, f32x4& N) {
  const u16* p = base + lane * 8;
#pragma unroll
  for (int g = 0; g < 3; ++g) {
    f32x4* a = (g == 0) ? &R : (g == 1) ? &Z : &N;
    bf16x8 whi = *(const bf16x8*)(p + (g * 2 + 0) * 512);
    bf16x8 wlo = *(const bf16x8*)(p + (g * 2 + 1) * 512);
    *a = __builtin_amdgcn_mfma_f32_16x16x32_bf16(ah, whi, *a, 0, 0, 0);
    *a = __builtin_amdgcn_mfma_f32_16x16x32_bf16(al, whi, *a, 0, 0, 0);
    *a = __builtin_amdgcn_mfma_f32_16x16x32_bf16(ah, wlo, *a, 0, 0, 0);
  }
}

// Multi-stream K=512 GEMM pipe. NS weight streams staged per kc (each 12KB:
// fc0+fc1), NA distinct A-streams (hi/lo sc1 loads). ALL 4 waves stage equal
// piece counts (NS*3 x 1KB LDS-DMA each) -> symmetric bundles, minimal barrier
// skew, uniform vmcnt accounting. Ring of DEPTH slots (slot = NS*12KB).
// Bundle = NS*3 + 2*NA vm-ops/wave. Raw s_barrier handoff; manual vmcnt.
template <int NS, int NA, int DEPTH>
__device__ __forceinline__ void pipeN(
    u16* ringb,
    const u16* (&Ahi)[NA], const u16* (&Alo)[NA],
    const u16* (&Wjb)[NS], const int (&ai)[NS],
    f32x4* (&acc)[NS][3],   // acc[s] = {R,Z,N}, each -> f32x4[2] (fc)
    int row0w, int lane, int wave) {
  constexpr int B = NS * 3 + 2 * NA;
  constexpr int SLOT = NS * 6144;  // u16 per ring slot
  const int quad = lane >> 4, n16 = lane & 15;
  const u16* aH[NA]; const u16* aL[NA];
#pragma unroll
  for (int n = 0; n < NA; ++n) {
    aH[n] = Ahi[n] + (size_t)(row0w + n16) * HD + quad * 8;
    aL[n] = Alo[n] + (size_t)(row0w + n16) * HD + quad * 8;
  }
  // Per-wave staging piece descriptors (hoisted out of the kc loop).
  const u16* srcB[NS * 3]; int dstO[NS * 3];
#pragma unroll
  for (int i = 0; i < NS * 3; ++i) {
    const int p = wave * (NS * 3) + i;
    const int s = p / 12, r = p % 12, f2 = r / 6, j = r % 6;
    const int co = f2 * 3072 + j * 512;
    srcB[i] = Wjb[s] + co + lane * 8;
    dstO[i] = s * 6144 + co;
  }
  u16* pb[DEPTH];
#pragma unroll
  for (int d = 0; d < DEPTH; ++d) pb[d] = ringb + d * SLOT;
  AFN<NA> af[DEPTH];

  auto issueB = [&](int ikc, int si) {
#pragma unroll
    for (int i = 0; i < NS * 3; ++i)
      __builtin_amdgcn_global_load_lds(
          (const glb_u32*)(srcB[i] + (size_t)ikc * 6144),
          (lds_u32*)(pb[si] + dstO[i]), 16, 0, 0);
#pragma unroll
    for (int n = 0; n < NA; ++n) {
      af[si].h[n] = load_sc16(aH[n] + ikc * 32);
      af[si].l[n] = load_sc16(aL[n] + ikc * 32);
    }
  };
  auto cons = [&](int si) {
    fence_afn(af[si]);
#pragma unroll
    for (int s = 0; s < NS; ++s)
#pragma unroll
      for (int f = 0; f < 2; ++f)
        mfma_kc9((const lds_u16*)(pb[si] + s * 6144 + f * 3072), lane,
                 af[si].h[ai[s]], af[si].l[ai[s]],
                 acc[s][0][f], acc[s][1][f], acc[s][2][f]);
  };

  WAIT_VM(0);  // drain unrelated vm-ops so bundle counting is exact
#pragma unroll
  for (int p = 0; p < DEPTH - 1; ++p) issueB(p, p);
  if constexpr (DEPTH == 4) {
#pragma unroll 1
    for (int kc = 0; kc < 12; kc += 4) {
      wvm<2 * B>(); bar_raw(); issueB(kc + 3, 3); cons(0);
      wvm<2 * B>(); bar_raw(); issueB(kc + 4, 0); cons(1);
      wvm<2 * B>(); bar_raw(); issueB(kc + 5, 1); cons(2);
      wvm<2 * B>(); bar_raw(); issueB(kc + 6, 2); cons(3);
    }
    wvm<2 * B>(); bar_raw(); issueB(15, 3); cons(0);  // kc=12
    wvm<2 * B>(); bar_raw(); cons(1);                 // kc=13
    wvm<B>();     bar_raw(); cons(2);                 // kc=14
    wvm<0>();     bar_raw(); cons(3);                 // kc=15
  } else {  // DEPTH == 3
#pragma unroll 1
    for (int kc = 0; kc < 12; kc += 3) {
      wvm<B>(); bar_raw(); issueB(kc + 2, 2); cons(0);
      wvm<B>(); bar_raw(); issueB(kc + 3, 0); cons(1);
      wvm<B>(); bar_raw(); issueB(kc + 4, 1); cons(2);
    }
    wvm<B>(); bar_raw(); issueB(14, 2); cons(0);  // kc=12
    wvm<B>(); bar_raw(); issueB(15, 0); cons(1);  // kc=13
    wvm<B>(); bar_raw(); cons(2);                 // kc=14
    wvm<0>(); bar_raw(); cons(0);                 // kc=15
  }
}

// x-phase for encoder L0: fp32 x[B,T,32], K=32, weights/x normal (L2-hot).
// One 16-row A-fragment feeds both fc weight chunks.
__device__ __forceinline__ void x_phase(const float* x, int t, const u16* Wp,
                                        int jb, int row0w, int lane,
                                        f32x4* aR, f32x4* aZ, f32x4* aN) {
  const int quad = lane >> 4, n16 = lane & 15;
  const float* xp = x + (size_t)(row0w + n16) * (TT * DIN) +
                    (size_t)t * DIN + quad * 8;
  f32x4 v0 = *(const f32x4*)xp;
  f32x4 v1 = *(const f32x4*)(xp + 4);
  bf16x8 hi, lo;
#pragma unroll
  for (int i = 0; i < 8; ++i) {
    float f = (i < 4) ? v0[i] : v1[i - 4];
    u16 h = (u16)(__float_as_uint(f) >> 16);
    hi[i] = (short)h;
    lo[i] = (short)f2bf_rne(f - bf2f(h));
  }
#pragma unroll
  for (int f = 0; f < 2; ++f)
    mfma_kc9_g(Wp + ((size_t)jb * 2 + f) * 3072, lane, hi, lo,
               aR[f], aZ[f], aN[f]);
}

// Row-group barrier (16 blocks sharing row0): every cross-block dependency in
// this kernel is row-preserving, so a 16-block barrier on a private counter
// line suffices. No cache invalidation: sc1 traffic already coherent.
__device__ __forceinline__ void gbar(unsigned* gen, unsigned target) {
  WAIT_VM(0);  // all this wave's sc1 stores / atomics globally visible
  __syncthreads();
  if (threadIdx.x == 0) {
    atomicAdd(gen, 1u);  // device-scope by default
    while (load_sc_u32w(gen) < target) __builtin_amdgcn_s_sleep(2);
  }
  __syncthreads();
}

// GRU epilogue with register-resident own-tile h (ho never re-read from mem).
__device__ __forceinline__ void gru_epi_reg(
    const float* bi, const float* bh, float (*ht)[4],
    u16* hnH, u16* hnL, int col0, int row0w, int quad,
    const f32x4* aR, const f32x4* aZ, const f32x4* aNX, const f32x4* aNH) {
#pragma unroll
  for (int f = 0; f < 2; ++f) {
    const int col = col0 + f * 16;
    const float bir = bi[col],          bhr = bh[col];
    const float biz = bi[HD + col],     bhz = bh[HD + col];
    const float bin = bi[2 * HD + col], bhn = bh[2 * HD + col];
#pragma unroll
    for (int r = 0; r < 4; ++r) {
      const int row = row0w + quad * 4 + r;
      const size_t idx = (size_t)row * HD + col;
      float rr = sigm(aR[f][r] + bir + bhr);
      float zz = sigm(aZ[f][r] + biz + bhz);
      float nn = tanh_(aNX[f][r] + bin + rr * (aNH[f][r] + bhn));
      float hv = (1.f - zz) * nn + zz * ht[f][r];
      ht[f][r] = hv;
      store_h_sc(hnH, hnL, idx, hv);
    }
  }
}

__global__ __launch_bounds__(256, 1)
void gru_persistent_kernel(
    const float* x,
    const u16* pkX0, const u16* pkH0, const float* bi0, const float* bh0,
    const u16* pkX1, const u16* pkH1, const float* bi1, const float* bh1,
    const u16* pkD0H, const float* dbi0, const float* dbh0, const float* dW0,
    const u16* pkD1I, const u16* pkD1H, const float* dbi1, const float* dbh1,
    const float* outW, const float* outb, const float* dstart,
    u16* h1aH, u16* h1aL, u16* h1bH, u16* h1bL,
    u16* h2aH, u16* h2aL, u16* h2bH, u16* h2bL,
    float* yfull, float* dout, unsigned* gen) {
  __shared__ u16 ring[3 * 3 * 6144];  // 108 KB: 3-slot triple-stream ring
  const int b = blockIdx.x;
  const int jb = (b & 7) * 2 + ((b >> 3) & 1);  // XCD-local jb
  const int row0 = (b >> 4) * 64;
  const int tid = threadIdx.x, wave = tid >> 6, lane = tid & 63;
  const int quad = lane >> 4, n16 = lane & 15;
  const int row0w = row0 + wave * 16;  // 4 waves = 4 row groups
  const int col0 = jb * 32 + n16;
  u16* ringb = &ring[0];
  const f32x4 z4 = {0.f, 0.f, 0.f, 0.f};
  const size_t jbs = (size_t)jb * (KC_H * 2 * 3072);  // jb slice base (K=512)
  const u16* pkH0j = pkH0 + jbs;
  const u16* pkX1j = pkX1 + jbs;
  const u16* pkH1j = pkH1 + jbs;
  const u16* pkD0Hj = pkD0H + jbs;
  const u16* pkD1Ij = pkD1I + jbs;
  const u16* pkD1Hj = pkD1H + jbs;
  // Per-row-group barrier counter: one u32 per group, 256-B line separation.
  unsigned* geng = gen + ((b >> 4) << 6);

  u16 *h1cH = h1aH, *h1cL = h1aL, *h1nH = h1bH, *h1nL = h1bL;
  u16 *h2cH = h2aH, *h2cL = h2aL, *h2nH = h2bH, *h2nL = h2bL;
  float ht1[2][4] = {{0, 0, 0, 0}, {0, 0, 0, 0}};  // own h1 tile (fc, r)
  float ht2[2][4] = {{0, 0, 0, 0}, {0, 0, 0, 0}};  // own h2 tile (fc, r)
  unsigned it = 0;

  // ---- encoder: 513 skewed phases; ONE merged pipe per step ----
  for (int k = 0; k <= TT; ++k) {
    f32x4 R0[2] = {z4, z4}, Z0[2] = {z4, z4}, NX0[2] = {z4, z4}, NH0[2] = {z4, z4};
    f32x4 R1[2] = {z4, z4}, Z1[2] = {z4, z4}, NX1[2] = {z4, z4}, NH1[2] = {z4, z4};
    if (k > 0 && k < TT) {
      // Triple: L0-h (pkH0*h1), L1-x (pkX1*h1), L1-h (pkH1*h2).
      const u16* Ah[2] = {h1cH, h2cH};
      const u16* Al[2] = {h1cL, h2cL};
      const u16* Wv[3] = {pkH0j, pkX1j, pkH1j};
      const int ai3[3] = {0, 0, 1};
      f32x4* ac[3][3] = {{R0, Z0, NH0}, {R1, Z1, NX1}, {R1, Z1, NH1}};
      pipeN<3, 2, 3>(ringb, Ah, Al, Wv, ai3, ac, row0w, lane, wave);
    } else if (k == 0) {
      const u16* Ah[1] = {h1cH};
      const u16* Al[1] = {h1cL};
      const u16* Wv[1] = {pkH0j};
      const int ai1[1] = {0};
      f32x4* ac[1][3] = {{R0, Z0, NH0}};
      pipeN<1, 1, 4>(ringb, Ah, Al, Wv, ai1, ac, row0w, lane, wave);
    } else {  // k == TT: L1-x + L1-h only
      const u16* Ah[2] = {h1cH, h2cH};
      const u16* Al[2] = {h1cL, h2cL};
      const u16* Wv[2] = {pkX1j, pkH1j};
      const int ai2[2] = {0, 1};
      f32x4* ac[2][3] = {{R1, Z1, NX1}, {R1, Z1, NH1}};
      pipeN<2, 2, 4>(ringb, Ah, Al, Wv, ai2, ac, row0w, lane, wave);
    }
    if (k < TT) {
      x_phase(x, k, pkX0, jb, row0w, lane, R0, Z0, NX0);
      gru_epi_reg(bi0, bh0, ht1, h1nH, h1nL, col0, row0w, quad, R0, Z0, NX0, NH0);
    }
    if (k > 0) {
      gru_epi_reg(bi1, bh1, ht2, h2nH, h2nL, col0, row0w, quad, R1, Z1, NX1, NH1);
    }
    gbar(geng, GRPB * (++it));
    if (k < TT) { u16* t0 = h1cH; h1cH = h1nH; h1nH = t0;
                  u16* t1 = h1cL; h1cL = h1nL; h1nL = t1; }
    if (k > 0)  { u16* t0 = h2cH; h2cH = h2nH; h2nH = t0;
                  u16* t1 = h2cL; h2cL = h2nL; h2nL = t1; }
  }

  // ---- decoder: 96 steps x (L0, L1); y via atomics into yfull[2][BB] ----
  for (int t = 0; t < PP; ++t) {
    {  // dec L0
      f32x4 R[2] = {z4, z4}, Z[2] = {z4, z4}, NH[2] = {z4, z4};
      {
        const u16* Ah[1] = {h1cH};
        const u16* Al[1] = {h1cL};
        const u16* Wv[1] = {pkD0Hj};
        const int ai1[1] = {0};
        f32x4* ac[1][3] = {{R, Z, NH}};
        pipeN<1, 1, 4>(ringb, Ah, Al, Wv, ai1, ac, row0w, lane, wave);
      }
      float yl[4] = {0, 0, 0, 0};
      if (t > 0) {
        const float* yb = yfull + ((t - 1) & 1) * BB;
#pragma unroll
        for (int r = 0; r < 4; ++r) {
          const float* p = yb + (row0w + quad * 4 + r);
          asm volatile("global_load_dword %0, %1, off sc0 sc1"
                       : "=&v"(yl[r]) : "v"(p) : "memory");
        }
        WAIT_VM(0);
#pragma unroll
        for (int r = 0; r < 4; ++r)
          asm volatile("" : "+v"(yl[r]));
      }
      const float ds0 = dstart[0], ob0 = outb[0];
#pragma unroll
      for (int f = 0; f < 2; ++f) {
        const int col = col0 + f * 16;
        const float bir = dbi0[col],          bhr = dbh0[col];
        const float biz = dbi0[HD + col],     bhz = dbh0[HD + col];
        const float bin = dbi0[2 * HD + col], bhn = dbh0[2 * HD + col];
        const float w0r = dW0[col], w0z = dW0[HD + col], w0n = dW0[2 * HD + col];
#pragma unroll
        for (int r = 0; r < 4; ++r) {
          const int row = row0w + quad * 4 + r;
          const size_t idx = (size_t)row * HD + col;
          float yv = (t == 0) ? ds0 : (ob0 + yl[r]);
          if (f == 0 && t > 0 && jb == 0 && n16 == 0)
            dout[(size_t)row * PP + (t - 1)] = yv;
          float rr = sigm(R[f][r] + bir + bhr + yv * w0r);
          float zz = sigm(Z[f][r] + biz + bhz + yv * w0z);
          float nn = tanh_(bin + yv * w0n + rr * (NH[f][r] + bhn));
          float hv = (1.f - zz) * nn + zz * ht1[f][r];
          ht1[f][r] = hv;
          store_h_sc(h1nH, h1nL, idx, hv);
        }
      }
    }
    gbar(geng, GRPB * (++it));
    {  // dec L1: merged dual pipe (pkD1I*h1n + pkD1H*h2c)
      f32x4 R[2] = {z4, z4}, Z[2] = {z4, z4}, NX[2] = {z4, z4}, NH[2] = {z4, z4};
      {
        const u16* Ah[2] = {h1nH, h2cH};
        const u16* Al[2] = {h1nL, h2cL};
        const u16* Wv[2] = {pkD1Ij, pkD1Hj};
        const int ai2[2] = {0, 1};
        f32x4* ac[2][3] = {{R, Z, NX}, {R, Z, NH}};
        pipeN<2, 2, 4>(ringb, Ah, Al, Wv, ai2, ac, row0w, lane, wave);
      }
      float vs[4] = {0, 0, 0, 0};
#pragma unroll
      for (int f = 0; f < 2; ++f) {
        const int col = col0 + f * 16;
        const float bir = dbi1[col],          bhr = dbh1[col];
        const float biz = dbi1[HD + col],     bhz = dbh1[HD + col];
        const float bin = dbi1[2 * HD + col], bhn = dbh1[2 * HD + col];
        const float wo = outW[col];
#pragma unroll
        for (int r = 0; r < 4; ++r) {
          const int row = row0w + quad * 4 + r;
          const size_t idx = (size_t)row * HD + col;
          float rr = sigm(R[f][r] + bir + bhr);
          float zz = sigm(Z[f][r] + biz + bhz);
          float nn = tanh_(NX[f][r] + bin + rr * (NH[f][r] + bhn));
          float hv = (1.f - zz) * nn + zz * ht2[f][r];
          ht2[f][r] = hv;
          store_h_sc(h2nH, h2nL, idx, hv);
          float v = hv * wo;
#pragma unroll
          for (int off = 1; off < 16; off <<= 1) v += __shfl_xor(v, off, 16);
          vs[r] += v;
        }
      }
      float* yw = yfull + (t & 1) * BB;
      float* yz = yfull + ((t - 1) & 1) * BB;
#pragma unroll
      for (int r = 0; r < 4; ++r) {
        const int row = row0w + quad * 4 + r;
        if (n16 == 0) {
          atomicAdd(yw + row, vs[r]);
          // zero last parity (read by dec L0 this iter; rewritten at t+1)
          if (t > 0 && jb == 0) store_sc_f32(yz + row, 0.f);
        }
      }
    }
    gbar(geng, GRPB * (++it));
    { u16* t0 = h1cH; h1cH = h1nH; h1nH = t0;
      u16* t1 = h1cL; h1cL = h1nL; h1nL = t1; }
    { u16* t0 = h2cH; h2cH = h2nH; h2nH = t0;
      u16* t1 = h2cL; h2cL = h2nL; h2nL = t1; }
  }

  // ---- finalize: y(P-1), group-local (each group's jb==0 block owns its
  // 64 rows; last gbar guarantees peer atomicAdds are visible) ----
  if ((b & 15) == 0 && tid < 64) {
    int row = row0 + tid;
    float v = load_sc_f32w(yfull + ((PP - 1) & 1) * BB + row);
    dout[(size_t)row * PP + (PP - 1)] = outb[0] + v;
  }
}

extern "C" void kernel_launch(void* const* d_in, const int* in_sizes, int n_in,
                              void* d_out, int out_size, void* d_ws, size_t ws_size,
                              hipStream_t stream) {
  const float* x      = (const float*)d_in[0];
  const float* eW_ih0 = (const float*)d_in[1];
  const float* eW_hh0 = (const float*)d_in[2];
  const float* eb_ih0 = (const float*)d_in[3];
  const float* eb_hh0 = (const float*)d_in[4];
  const float* eW_ih1 = (const float*)d_in[5];
  const float* eW_hh1 = (const float*)d_in[6];
  const float* eb_ih1 = (const float*)d_in[7];
  const float* eb_hh1 = (const float*)d_in[8];
  const float* dW_ih0 = (const float*)d_in[9];
  const float* dW_hh0 = (const float*)d_in[10];
  const float* db_ih0 = (const float*)d_in[11];
  const float* db_hh0 = (const float*)d_in[12];
  const float* dW_ih1 = (const float*)d_in[13];
  const float* dW_hh1 = (const float*)d_in[14];
  const float* db_ih1 = (const float*)d_in[15];
  const float* db_hh1 = (const float*)d_in[16];
  const float* outW   = (const float*)d_in[17];
  const float* outb   = (const float*)d_in[18];
  const float* dstart = (const float*)d_in[19];
  float* out = (float*)d_out;

  char* w = (char*)d_ws;
  size_t off = 0;
  auto carve = [&](size_t bytes) -> void* {
    void* p = w + off;
    off = (off + bytes + 255) & ~(size_t)255;
    return p;
  };
  u16* h1aH = (u16*)carve((size_t)BB * HD * 2); u16* h1aL = (u16*)carve((size_t)BB * HD * 2);
  u16* h1bH = (u16*)carve((size_t)BB * HD * 2); u16* h1bL = (u16*)carve((size_t)BB * HD * 2);
  u16* h2aH = (u16*)carve((size_t)BB * HD * 2); u16* h2aL = (u16*)carve((size_t)BB * HD * 2);
  u16* h2bH = (u16*)carve((size_t)BB * HD * 2); u16* h2bL = (u16*)carve((size_t)BB * HD * 2);
  float* yfull = (float*)carve((size_t)2 * BB * 4);
  unsigned* gen = (unsigned*)carve(4096);  // 16 group counters, 256-B stride
  auto carve_pack = [&](int K) -> u16* {
    return (u16*)carve((size_t)3 * HD * K * 2 * 2);
  };
  u16* pk_e0ih = carve_pack(DIN);
  u16* pk_e0hh = carve_pack(HD);
  u16* pk_e1ih = carve_pack(HD);
  u16* pk_e1hh = carve_pack(HD);
  u16* pk_d0hh = carve_pack(HD);
  u16* pk_d1ih = carve_pack(HD);
  u16* pk_d1hh = carve_pack(HD);

  hipMemsetAsync(h1aH, 0, (size_t)BB * HD * 2, stream);
  hipMemsetAsync(h1aL, 0, (size_t)BB * HD * 2, stream);
  hipMemsetAsync(h2aH, 0, (size_t)BB * HD * 2, stream);
  hipMemsetAsync(h2aL, 0, (size_t)BB * HD * 2, stream);
  hipMemsetAsync(yfull, 0, (size_t)2 * BB * 4, stream);
  hipMemsetAsync(gen, 0, 4096, stream);

  auto pack = [&](const float* W, int K, u16* dst) {
    int total = 16 * (K >> 5) * 2 * 6 * 64;
    pack_w_kernel<<<(total + 255) / 256, 256, 0, stream>>>(W, K, dst);
  };
  pack(eW_ih0, DIN, pk_e0ih);
  pack(eW_hh0, HD, pk_e0hh);
  pack(eW_ih1, HD, pk_e1ih);
  pack(eW_hh1, HD, pk_e1hh);
  pack(dW_hh0, HD, pk_d0hh);
  pack(dW_ih1, HD, pk_d1ih);
  pack(dW_hh1, HD, pk_d1hh);

  gru_persistent_kernel<<<NBLK, 256, 0, stream>>>(
      x, pk_e0ih, pk_e0hh, eb_ih0, eb_hh0,
      pk_e1ih, pk_e1hh, eb_ih1, eb_hh1,
      pk_d0hh, db_ih0, db_hh0, dW_ih0,
      pk_d1ih, pk_d1hh, db_ih1, db_hh1,
      outW, outb, dstart,
      h1aH, h1aL, h1bH, h1bL, h2aH, h2aL, h2bH, h2bL,
      yfull, out, gen);
}

// Round 6
// 16132.799 us; speedup vs baseline: 1.2900x; 1.0084x over previous
//
#include <hip/hip_runtime.h>

#define HD 512
#define BB 1024
#define TT 512
#define PP 96
#define DIN 32
#define KC_H 16
#define NBLK 256
#define GRPB 16  // blocks per row-group barrier (all 16 jb of one row group)

typedef unsigned short u16;
typedef __attribute__((ext_vector_type(8))) short bf16x8;
typedef __attribute__((ext_vector_type(4))) float f32x4;
typedef __attribute__((address_space(3))) unsigned int lds_u32;
typedef __attribute__((address_space(3))) u16 lds_u16;
typedef __attribute__((address_space(1))) unsigned int glb_u32;

#define WAIT_VM(N) asm volatile("s_waitcnt vmcnt(" #N ")" ::: "memory")
__device__ __forceinline__ void bar_raw() { asm volatile("s_barrier" ::: "memory"); }

template <int N> __device__ __forceinline__ void wvm() {
  if constexpr (N == 0) WAIT_VM(0);
  else if constexpr (N == 2) WAIT_VM(2);
  else if constexpr (N == 4) WAIT_VM(4);
  else if constexpr (N == 5) WAIT_VM(5);
  else if constexpr (N == 10) WAIT_VM(10);
  else if constexpr (N == 13) WAIT_VM(13);
}

__device__ __forceinline__ float bf2f(u16 s) {
  return __uint_as_float(((unsigned)s) << 16);
}
__device__ __forceinline__ u16 f2bf_rne(float f) {
  unsigned u = __float_as_uint(f);
  u += 0x7FFF + ((u >> 16) & 1);
  return (u16)(u >> 16);
}
__device__ __forceinline__ float sigm(float v) { return 1.f / (1.f + __expf(-v)); }
__device__ __forceinline__ float tanh_(float a) {
  return 1.f - 2.f / (__expf(2.f * a) + 1.f);
}

// ---- coherent (L2-bypass) access helpers: sc0 sc1 ----
__device__ __forceinline__ bf16x8 load_sc16(const u16* p) {
  bf16x8 r;
  asm volatile("global_load_dwordx4 %0, %1, off sc0 sc1" : "=&v"(r) : "v"(p) : "memory");
  return r;
}
__device__ __forceinline__ void store_sc_u16(u16* p, unsigned v) {
  asm volatile("global_store_short %0, %1, off sc0 sc1" :: "v"(p), "v"(v) : "memory");
}
__device__ __forceinline__ void store_sc_f32(float* p, float v) {
  asm volatile("global_store_dword %0, %1, off sc0 sc1" :: "v"(p), "v"(v) : "memory");
}
__device__ __forceinline__ float load_sc_f32w(const float* p) {  // load + full wait
  float v;
  asm volatile("global_load_dword %0, %1, off sc0 sc1\ns_waitcnt vmcnt(0)"
               : "=&v"(v) : "v"(p) : "memory");
  return v;
}
__device__ __forceinline__ unsigned load_sc_u32w(const unsigned* p) {
  unsigned v;
  asm volatile("global_load_dword %0, %1, off sc0 sc1\ns_waitcnt vmcnt(0)"
               : "=&v"(v) : "v"(p) : "memory");
  return v;
}
__device__ __forceinline__ void store_h_sc(u16* H, u16* L, size_t idx, float hv) {
  u16 hi = (u16)(__float_as_uint(hv) >> 16);  // trunc; lo corrects
  u16 lo = f2bf_rne(hv - bf2f(hi));
  store_sc_u16(H + idx, (unsigned)hi);
  store_sc_u16(L + idx, (unsigned)lo);
}

// Pack fp32 weight W[3H x K] into fc-contiguous MFMA B-frag bf16 hi/lo layout:
// group512 = ((jb*KC + kc)*2 + fc)*6 + (g*2 + s);  u16 off = group*512 + lane*8
__global__ void pack_w_kernel(const float* __restrict__ W, int K,
                              u16* __restrict__ out) {
  int tid = blockIdx.x * 256 + threadIdx.x;
  int KC = K >> 5;
  int total = 16 * KC * 2 * 6 * 64;
  if (tid >= total) return;
  int lane = tid & 63;
  int rest = tid >> 6;
  int gs = rest % 6; rest /= 6;
  int fc = rest & 1; rest >>= 1;
  int kc = rest % KC;
  int jb = rest / KC;
  int g = gs >> 1, s = gs & 1;
  int j = jb * 32 + fc * 16 + (lane & 15);
  int k = kc * 32 + (lane >> 4) * 8;
  const float* src = W + (size_t)(g * HD + j) * K + k;
  bf16x8 v;
#pragma unroll
  for (int i = 0; i < 8; ++i) {
    float f = src[i];
    u16 hi = f2bf_rne(f);
    v[i] = (short)((s == 0) ? hi : f2bf_rne(f - bf2f(hi)));
  }
  *(bf16x8*)(out + (size_t)tid * 8) = v;
}

// A fragments for NA distinct A-streams (hi/lo split bf16).
template <int NA> struct AFN { bf16x8 h[NA]; bf16x8 l[NA]; };
template <int NA>
__device__ __forceinline__ void fence_afn(AFN<NA>& a) {
#pragma unroll
  for (int n = 0; n < NA; ++n)
    asm volatile("" : "+v"(a.h[n]), "+v"(a.l[n]));
}

// 9 MFMAs for one (stream, fc) 6KB chunk (6 frag groups of 512 u16).
__device__ __forceinline__ void mfma_kc9(const lds_u16* base, int lane,
                                         bf16x8 ah, bf16x8 al,
                                         f32x4& R, f32x4& Z, f32x4& N) {
  typedef __attribute__((address_space(3))) const bf16x8 lds_bf16x8;
  const lds_u16* p = base + lane * 8;
#pragma unroll
  for (int g = 0; g < 3; ++g) {
    f32x4* a = (g == 0) ? &R : (g == 1) ? &Z : &N;
    bf16x8 whi = *(lds_bf16x8*)(p + (g * 2 + 0) * 512);
    bf16x8 wlo = *(lds_bf16x8*)(p + (g * 2 + 1) * 512);
    *a = __builtin_amdgcn_mfma_f32_16x16x32_bf16(ah, whi, *a, 0, 0, 0);
    *a = __builtin_amdgcn_mfma_f32_16x16x32_bf16(al, whi, *a, 0, 0, 0);
    *a = __builtin_amdgcn_mfma_f32_16x16x32_bf16(ah, wlo, *a, 0, 0, 0);
  }
}
// Global variant for the K=32 x-phase (L2-hot, compiler-managed waits).
__device__ __forceinline__ void mfma_kc9_g(const u16* base, int lane,
                                           bf16x8 ah, bf16x8 al,
                                           f32x4& R, f32x4& Z, f32x4& N) {
  const u16* p = base + lane * 8;
#pragma unroll
  for (int g = 0; g < 3; ++g) {
    f32x4* a = (g == 0) ? &R : (g == 1) ? &Z : &N;
    bf16x8 whi = *(const bf16x8*)(p + (g * 2 + 0) * 512);
    bf16x8 wlo = *(const bf16x8*)(p + (g * 2 + 1) * 512);
    *a = __builtin_amdgcn_mfma_f32_16x16x32_bf16(ah, whi, *a, 0, 0, 0);
    *a = __builtin_amdgcn_mfma_f32_16x16x32_bf16(al, whi, *a, 0, 0, 0);
    *a = __builtin_amdgcn_mfma_f32_16x16x32_bf16(ah, wlo, *a, 0, 0, 0);
  }
}

// Weight-piece mapping shared by prefetch and pipe: NS streams x 12 x 1KB
// pieces; each of 4 waves stages NS*3 pieces per kc.
template <int NS>
__device__ __forceinline__ void piece_map(const u16* const (&Wjb)[NS],
                                          int lane, int wave,
                                          const u16* (&srcB)[NS * 3],
                                          int (&dstO)[NS * 3]) {
#pragma unroll
  for (int i = 0; i < NS * 3; ++i) {
    const int p = wave * (NS * 3) + i;
    const int s = p / 12, r = p % 12, f2 = r / 6, j = r % 6;
    const int co = f2 * 3072 + j * 512;
    srcB[i] = Wjb[s] + co + lane * 8;
    dstO[i] = s * 6144 + co;
  }
}

// Prefetch (barrier-shadow): stage weight kc=0 -> slot0, kc=1 -> slot1 of the
// UPCOMING pipe's ring layout. Weights are read-only, so this is legal before
// the row-group barrier completes.
template <int NS>
__device__ __forceinline__ void stageW2(u16* ringb, const u16* const (&Wjb)[NS],
                                        int lane, int wave) {
  const u16* srcB[NS * 3]; int dstO[NS * 3];
  piece_map<NS>(Wjb, lane, wave, srcB, dstO);
#pragma unroll
  for (int ikc = 0; ikc < 2; ++ikc)
#pragma unroll
    for (int i = 0; i < NS * 3; ++i)
      __builtin_amdgcn_global_load_lds(
          (const glb_u32*)(srcB[i] + (size_t)ikc * 6144),
          (lds_u32*)(ringb + (size_t)ikc * NS * 6144 + dstO[i]), 16, 0, 0);
}

// Multi-stream K=512 GEMM pipe, depth-3 ring, PREFETCHED slots 0,1 (weights
// already in LDS from the barrier-shadow stageW2). Entry issues only the
// A-loads for slots 0,1; steady state = full bundles (NS*3 DMA + 2*NA sc
// A-loads). All 4 waves stage equal piece counts. Raw s_barrier handoff.
template <int NS, int NA>
__device__ __forceinline__ void pipePre(
    u16* ringb,
    const u16* const (&Ahi)[NA], const u16* const (&Alo)[NA],
    const u16* const (&Wjb)[NS], const int (&ai)[NS],
    f32x4* (&acc)[NS][3],   // acc[s] = {R,Z,N}, each -> f32x4[2] (fc)
    int row0w, int lane, int wave) {
  constexpr int B = NS * 3 + 2 * NA;
  constexpr int A2 = 2 * NA;
  constexpr int SLOT = NS * 6144;
  const int quad = lane >> 4, n16 = lane & 15;
  const u16* aH[NA]; const u16* aL[NA];
#pragma unroll
  for (int n = 0; n < NA; ++n) {
    aH[n] = Ahi[n] + (size_t)(row0w + n16) * HD + quad * 8;
    aL[n] = Alo[n] + (size_t)(row0w + n16) * HD + quad * 8;
  }
  const u16* srcB[NS * 3]; int dstO[NS * 3];
  piece_map<NS>(Wjb, lane, wave, srcB, dstO);
  u16* pb[3] = {ringb, ringb + SLOT, ringb + 2 * SLOT};
  AFN<NA> af0, af1, af2;

  auto issueA = [&](int ikc, AFN<NA>& dst) {
#pragma unroll
    for (int n = 0; n < NA; ++n) {
      dst.h[n] = load_sc16(aH[n] + ikc * 32);
      dst.l[n] = load_sc16(aL[n] + ikc * 32);
    }
  };
  auto issueB = [&](int ikc, int si, AFN<NA>& dst) {
#pragma unroll
    for (int i = 0; i < NS * 3; ++i)
      __builtin_amdgcn_global_load_lds(
          (const glb_u32*)(srcB[i] + (size_t)ikc * 6144),
          (lds_u32*)(pb[si] + dstO[i]), 16, 0, 0);
    issueA(ikc, dst);
  };
  auto cons = [&](int si, AFN<NA>& a) {
    fence_afn(a);
#pragma unroll
    for (int s = 0; s < NS; ++s)
#pragma unroll
      for (int f = 0; f < 2; ++f)
        mfma_kc9((const lds_u16*)(pb[si] + s * 6144 + f * 3072), lane,
                 a.h[ai[s]], a.l[ai[s]],
                 acc[s][0][f], acc[s][1][f], acc[s][2][f]);
  };

  WAIT_VM(0);  // drain own prefetch DMAs (slots 0,1 weights)
  issueA(0, af0);
  issueA(1, af1);
  wvm<A2>(); bar_raw(); issueB(2, 2, af2); cons(0, af0);   // kc=0
  wvm<B>();  bar_raw(); issueB(3, 0, af0); cons(1, af1);   // kc=1
#pragma unroll 1
  for (int q = 0; q < 4; ++q) {  // kc = 2+3q, 3+3q, 4+3q  (covers 2..13)
    const int base = 4 + q * 3;  // ikc of first issue
    wvm<B>(); bar_raw(); issueB(base + 0, 1, af1); cons(2, af2);
    wvm<B>(); bar_raw(); issueB(base + 1, 2, af2); cons(0, af0);
    wvm<B>(); bar_raw(); issueB(base + 2, 0, af0); cons(1, af1);
  }
  wvm<B>(); bar_raw(); cons(2, af2);   // kc=14
  wvm<0>(); bar_raw(); cons(0, af0);   // kc=15
}

// x-accumulate for encoder L0: fp32 x[B,T,32], K=32, weights/x normal
// (L2-hot). Runs in the barrier shadow; accumulates into xR/xZ/xN.
__device__ __forceinline__ void x_acc(const float* x, int t, const u16* Wp,
                                      int jb, int row0w, int lane,
                                      f32x4* aR, f32x4* aZ, f32x4* aN) {
  const int quad = lane >> 4, n16 = lane & 15;
  const float* xp = x + (size_t)(row0w + n16) * (TT * DIN) +
                    (size_t)t * DIN + quad * 8;
  f32x4 v0 = *(const f32x4*)xp;
  f32x4 v1 = *(const f32x4*)(xp + 4);
  bf16x8 hi, lo;
#pragma unroll
  for (int i = 0; i < 8; ++i) {
    float f = (i < 4) ? v0[i] : v1[i - 4];
    u16 h = (u16)(__float_as_uint(f) >> 16);
    hi[i] = (short)h;
    lo[i] = (short)f2bf_rne(f - bf2f(h));
  }
#pragma unroll
  for (int f = 0; f < 2; ++f)
    mfma_kc9_g(Wp + ((size_t)jb * 2 + f) * 3072, lane, hi, lo,
               aR[f], aZ[f], aN[f]);
}

// Row-group barrier, split arrive/wait: the window between them is filled
// with next-step weight prefetch + x-phase (peer-independent work).
__device__ __forceinline__ void gbar_arrive(unsigned* gen) {
  WAIT_VM(0);  // all this wave's sc1 stores / atomics globally visible
  __syncthreads();
  if (threadIdx.x == 0) atomicAdd(gen, 1u);  // device-scope by default
}
__device__ __forceinline__ void gbar_wait(unsigned* gen, unsigned target) {
  if (threadIdx.x == 0) {
    while (load_sc_u32w(gen) < target) __builtin_amdgcn_s_sleep(2);
  }
  __syncthreads();
}

// GRU epilogue with register-resident own-tile h (ho never re-read from mem).
__device__ __forceinline__ void gru_epi_reg(
    const float* bi, const float* bh, float (*ht)[4],
    u16* hnH, u16* hnL, int col0, int row0w, int quad,
    const f32x4* aR, const f32x4* aZ, const f32x4* aNX, const f32x4* aNH) {
#pragma unroll
  for (int f = 0; f < 2; ++f) {
    const int col = col0 + f * 16;
    const float bir = bi[col],          bhr = bh[col];
    const float biz = bi[HD + col],     bhz = bh[HD + col];
    const float bin = bi[2 * HD + col], bhn = bh[2 * HD + col];
#pragma unroll
    for (int r = 0; r < 4; ++r) {
      const int row = row0w + quad * 4 + r;
      const size_t idx = (size_t)row * HD + col;
      float rr = sigm(aR[f][r] + bir + bhr);
      float zz = sigm(aZ[f][r] + biz + bhz);
      float nn = tanh_(aNX[f][r] + bin + rr * (aNH[f][r] + bhn));
      float hv = (1.f - zz) * nn + zz * ht[f][r];
      ht[f][r] = hv;
      store_h_sc(hnH, hnL, idx, hv);
    }
  }
}

__global__ __launch_bounds__(256, 1)
void gru_persistent_kernel(
    const float* x,
    const u16* pkX0, const u16* pkH0, const float* bi0, const float* bh0,
    const u16* pkX1, const u16* pkH1, const float* bi1, const float* bh1,
    const u16* pkD0H, const float* dbi0, const float* dbh0, const float* dW0,
    const u16* pkD1I, const u16* pkD1H, const float* dbi1, const float* dbh1,
    const float* outW, const float* outb, const float* dstart,
    u16* h1aH, u16* h1aL, u16* h1bH, u16* h1bL,
    u16* h2aH, u16* h2aL, u16* h2bH, u16* h2bL,
    float* yfull, float* dout, unsigned* gen) {
  __shared__ u16 ring[3 * 3 * 6144];  // 108 KB: 3-slot triple-stream ring
  const int b = blockIdx.x;
  const int jb = (b & 7) * 2 + ((b >> 3) & 1);  // XCD-local jb
  const int row0 = (b >> 4) * 64;
  const int tid = threadIdx.x, wave = tid >> 6, lane = tid & 63;
  const int quad = lane >> 4, n16 = lane & 15;
  const int row0w = row0 + wave * 16;  // 4 waves = 4 row groups
  const int col0 = jb * 32 + n16;
  u16* ringb = &ring[0];
  const f32x4 z4 = {0.f, 0.f, 0.f, 0.f};
  const size_t jbs = (size_t)jb * (KC_H * 2 * 3072);  // jb slice base (K=512)
  const u16* pkH0j = pkH0 + jbs;
  const u16* pkX1j = pkX1 + jbs;
  const u16* pkH1j = pkH1 + jbs;
  const u16* pkD0Hj = pkD0H + jbs;
  const u16* pkD1Ij = pkD1I + jbs;
  const u16* pkD1Hj = pkD1H + jbs;
  // Per-row-group barrier counter: one u32 per group, 256-B line separation.
  unsigned* geng = gen + ((b >> 4) << 6);

  u16 *h1cH = h1aH, *h1cL = h1aL, *h1nH = h1bH, *h1nL = h1bL;
  u16 *h2cH = h2aH, *h2cL = h2aL, *h2nH = h2bH, *h2nL = h2bL;
  float ht1[2][4] = {{0, 0, 0, 0}, {0, 0, 0, 0}};  // own h1 tile (fc, r)
  float ht2[2][4] = {{0, 0, 0, 0}, {0, 0, 0, 0}};  // own h2 tile (fc, r)
  unsigned it = 0;

  // x-phase accumulators for the upcoming encoder step (barrier-shadow).
  f32x4 xR[2] = {z4, z4}, xZ[2] = {z4, z4}, xN[2] = {z4, z4};
  {  // initial prefetch for k=0 single pipe + x-acc(0)
    const u16* Wv1[1] = {pkH0j};
    stageW2<1>(ringb, Wv1, lane, wave);
    x_acc(x, 0, pkX0, jb, row0w, lane, xR, xZ, xN);
  }

  // ---- encoder: 513 skewed phases; ONE merged pipe per step ----
  for (int k = 0; k <= TT; ++k) {
    f32x4 R0[2], Z0[2], NX0[2], NH0[2] = {z4, z4};
    f32x4 R1[2] = {z4, z4}, Z1[2] = {z4, z4}, NX1[2] = {z4, z4}, NH1[2] = {z4, z4};
    if (k < TT) {
      R0[0] = xR[0]; R0[1] = xR[1];
      Z0[0] = xZ[0]; Z0[1] = xZ[1];
      NX0[0] = xN[0]; NX0[1] = xN[1];
    } else {
      R0[0] = z4; R0[1] = z4; Z0[0] = z4; Z0[1] = z4; NX0[0] = z4; NX0[1] = z4;
    }
    if (k > 0 && k < TT) {
      // Triple: L0-h (pkH0*h1), L1-x (pkX1*h1), L1-h (pkH1*h2).
      const u16* Ah[2] = {h1cH, h2cH};
      const u16* Al[2] = {h1cL, h2cL};
      const u16* Wv[3] = {pkH0j, pkX1j, pkH1j};
      const int ai3[3] = {0, 0, 1};
      f32x4* ac[3][3] = {{R0, Z0, NH0}, {R1, Z1, NX1}, {R1, Z1, NH1}};
      pipePre<3, 2>(ringb, Ah, Al, Wv, ai3, ac, row0w, lane, wave);
    } else if (k == 0) {
      const u16* Ah[1] = {h1cH};
      const u16* Al[1] = {h1cL};
      const u16* Wv[1] = {pkH0j};
      const int ai1[1] = {0};
      f32x4* ac[1][3] = {{R0, Z0, NH0}};
      pipePre<1, 1>(ringb, Ah, Al, Wv, ai1, ac, row0w, lane, wave);
    } else {  // k == TT: L1-x + L1-h only
      const u16* Ah[2] = {h1cH, h2cH};
      const u16* Al[2] = {h1cL, h2cL};
      const u16* Wv[2] = {pkX1j, pkH1j};
      const int ai2[2] = {0, 1};
      f32x4* ac[2][3] = {{R1, Z1, NX1}, {R1, Z1, NH1}};
      pipePre<2, 2>(ringb, Ah, Al, Wv, ai2, ac, row0w, lane, wave);
    }
    if (k < TT)
      gru_epi_reg(bi0, bh0, ht1, h1nH, h1nL, col0, row0w, quad, R0, Z0, NX0, NH0);
    if (k > 0)
      gru_epi_reg(bi1, bh1, ht2, h2nH, h2nL, col0, row0w, quad, R1, Z1, NX1, NH1);
    ++it;
    gbar_arrive(geng);
    // ---- barrier shadow: peer-independent work ----
    if (k + 1 < TT) {
      xR[0] = z4; xR[1] = z4; xZ[0] = z4; xZ[1] = z4; xN[0] = z4; xN[1] = z4;
      x_acc(x, k + 1, pkX0, jb, row0w, lane, xR, xZ, xN);
    }
    if (k + 1 < TT) {
      const u16* Wv3[3] = {pkH0j, pkX1j, pkH1j};
      stageW2<3>(ringb, Wv3, lane, wave);
    } else if (k + 1 == TT) {
      const u16* Wv2[2] = {pkX1j, pkH1j};
      stageW2<2>(ringb, Wv2, lane, wave);
    } else {  // k == TT -> next is decoder L0 (single)
      const u16* Wv1[1] = {pkD0Hj};
      stageW2<1>(ringb, Wv1, lane, wave);
    }
    gbar_wait(geng, GRPB * it);
    if (k < TT) { u16* t0 = h1cH; h1cH = h1nH; h1nH = t0;
                  u16* t1 = h1cL; h1cL = h1nL; h1nL = t1; }
    if (k > 0)  { u16* t0 = h2cH; h2cH = h2nH; h2nH = t0;
                  u16* t1 = h2cL; h2cL = h2nL; h2nL = t1; }
  }

  // ---- decoder: 96 steps x (L0, L1); y via atomics into yfull[2][BB] ----
  for (int t = 0; t < PP; ++t) {
    {  // dec L0
      f32x4 R[2] = {z4, z4}, Z[2] = {z4, z4}, NH[2] = {z4, z4};
      {
        const u16* Ah[1] = {h1cH};
        const u16* Al[1] = {h1cL};
        const u16* Wv[1] = {pkD0Hj};
        const int ai1[1] = {0};
        f32x4* ac[1][3] = {{R, Z, NH}};
        pipePre<1, 1>(ringb, Ah, Al, Wv, ai1, ac, row0w, lane, wave);
      }
      float yl[4] = {0, 0, 0, 0};
      if (t > 0) {
        const float* yb = yfull + ((t - 1) & 1) * BB;
#pragma unroll
        for (int r = 0; r < 4; ++r) {
          const float* p = yb + (row0w + quad * 4 + r);
          asm volatile("global_load_dword %0, %1, off sc0 sc1"
                       : "=&v"(yl[r]) : "v"(p) : "memory");
        }
        WAIT_VM(0);
#pragma unroll
        for (int r = 0; r < 4; ++r)
          asm volatile("" : "+v"(yl[r]));
      }
      const float ds0 = dstart[0], ob0 = outb[0];
#pragma unroll
      for (int f = 0; f < 2; ++f) {
        const int col = col0 + f * 16;
        const float bir = dbi0[col],          bhr = dbh0[col];
        const float biz = dbi0[HD + col],     bhz = dbh0[HD + col];
        const float bin = dbi0[2 * HD + col], bhn = dbh0[2 * HD + col];
        const float w0r = dW0[col], w0z = dW0[HD + col], w0n = dW0[2 * HD + col];
#pragma unroll
        for (int r = 0; r < 4; ++r) {
          const int row = row0w + quad * 4 + r;
          const size_t idx = (size_t)row * HD + col;
          float yv = (t == 0) ? ds0 : (ob0 + yl[r]);
          if (f == 0 && t > 0 && jb == 0 && n16 == 0)
            dout[(size_t)row * PP + (t - 1)] = yv;
          float rr = sigm(R[f][r] + bir + bhr + yv * w0r);
          float zz = sigm(Z[f][r] + biz + bhz + yv * w0z);
          float nn = tanh_(bin + yv * w0n + rr * (NH[f][r] + bhn));
          float hv = (1.f - zz) * nn + zz * ht1[f][r];
          ht1[f][r] = hv;
          store_h_sc(h1nH, h1nL, idx, hv);
        }
      }
    }
    ++it;
    gbar_arrive(geng);
    {  // barrier shadow: prefetch dual {D1I, D1H}
      const u16* Wv2[2] = {pkD1Ij, pkD1Hj};
      stageW2<2>(ringb, Wv2, lane, wave);
    }
    gbar_wait(geng, GRPB * it);
    {  // dec L1: merged dual pipe (pkD1I*h1n + pkD1H*h2c)
      f32x4 R[2] = {z4, z4}, Z[2] = {z4, z4}, NX[2] = {z4, z4}, NH[2] = {z4, z4};
      {
        const u16* Ah[2] = {h1nH, h2cH};
        const u16* Al[2] = {h1nL, h2cL};
        const u16* Wv[2] = {pkD1Ij, pkD1Hj};
        const int ai2[2] = {0, 1};
        f32x4* ac[2][3] = {{R, Z, NX}, {R, Z, NH}};
        pipePre<2, 2>(ringb, Ah, Al, Wv, ai2, ac, row0w, lane, wave);
      }
      float vs[4] = {0, 0, 0, 0};
#pragma unroll
      for (int f = 0; f < 2; ++f) {
        const int col = col0 + f * 16;
        const float bir = dbi1[col],          bhr = dbh1[col];
        const float biz = dbi1[HD + col],     bhz = dbh1[HD + col];
        const float bin = dbi1[2 * HD + col], bhn = dbh1[2 * HD + col];
        const float wo = outW[col];
#pragma unroll
        for (int r = 0; r < 4; ++r) {
          const int row = row0w + quad * 4 + r;
          const size_t idx = (size_t)row * HD + col;
          float rr = sigm(R[f][r] + bir + bhr);
          float zz = sigm(Z[f][r] + biz + bhz);
          float nn = tanh_(NX[f][r] + bin + rr * (NH[f][r] + bhn));
          float hv = (1.f - zz) * nn + zz * ht2[f][r];
          ht2[f][r] = hv;
          store_h_sc(h2nH, h2nL, idx, hv);
          float v = hv * wo;
#pragma unroll
          for (int off = 1; off < 16; off <<= 1) v += __shfl_xor(v, off, 16);
          vs[r] += v;
        }
      }
      float* yw = yfull + (t & 1) * BB;
      float* yz = yfull + ((t - 1) & 1) * BB;
#pragma unroll
      for (int r = 0; r < 4; ++r) {
        const int row = row0w + quad * 4 + r;
        if (n16 == 0) {
          atomicAdd(yw + row, vs[r]);
          // zero last parity (read by dec L0 this iter; rewritten at t+1)
          if (t > 0 && jb == 0) store_sc_f32(yz + row, 0.f);
        }
      }
    }
    ++it;
    gbar_arrive(geng);
    if (t + 1 < PP) {  // barrier shadow: prefetch next dec L0 single
      const u16* Wv1[1] = {pkD0Hj};
      stageW2<1>(ringb, Wv1, lane, wave);
    }
    gbar_wait(geng, GRPB * it);
    { u16* t0 = h1cH; h1cH = h1nH; h1nH = t0;
      u16* t1 = h1cL; h1cL = h1nL; h1nL = t1; }
    { u16* t0 = h2cH; h2cH = h2nH; h2nH = t0;
      u16* t1 = h2cL; h2cL = h2nL; h2nL = t1; }
  }

  // ---- finalize: y(P-1), group-local (each group's jb==0 block owns its
  // 64 rows; last gbar guarantees peer atomicAdds are visible) ----
  if ((b & 15) == 0 && tid < 64) {
    int row = row0 + tid;
    float v = load_sc_f32w(yfull + ((PP - 1) & 1) * BB + row);
    dout[(size_t)row * PP + (PP - 1)] = outb[0] + v;
  }
}

extern "C" void kernel_launch(void* const* d_in, const int* in_sizes, int n_in,
                              void* d_out, int out_size, void* d_ws, size_t ws_size,
                              hipStream_t stream) {
  const float* x      = (const float*)d_in[0];
  const float* eW_ih0 = (const float*)d_in[1];
  const float* eW_hh0 = (const float*)d_in[2];
  const float* eb_ih0 = (const float*)d_in[3];
  const float* eb_hh0 = (const float*)d_in[4];
  const float* eW_ih1 = (const float*)d_in[5];
  const float* eW_hh1 = (const float*)d_in[6];
  const float* eb_ih1 = (const float*)d_in[7];
  const float* eb_hh1 = (const float*)d_in[8];
  const float* dW_ih0 = (const float*)d_in[9];
  const float* dW_hh0 = (const float*)d_in[10];
  const float* db_ih0 = (const float*)d_in[11];
  const float* db_hh0 = (const float*)d_in[12];
  const float* dW_ih1 = (const float*)d_in[13];
  const float* dW_hh1 = (const float*)d_in[14];
  const float* db_ih1 = (const float*)d_in[15];
  const float* db_hh1 = (const float*)d_in[16];
  const float* outW   = (const float*)d_in[17];
  const float* outb   = (const float*)d_in[18];
  const float* dstart = (const float*)d_in[19];
  float* out = (float*)d_out;

  char* w = (char*)d_ws;
  size_t off = 0;
  auto carve = [&](size_t bytes) -> void* {
    void* p = w + off;
    off = (off + bytes + 255) & ~(size_t)255;
    return p;
  };
  u16* h1aH = (u16*)carve((size_t)BB * HD * 2); u16* h1aL = (u16*)carve((size_t)BB * HD * 2);
  u16* h1bH = (u16*)carve((size_t)BB * HD * 2); u16* h1bL = (u16*)carve((size_t)BB * HD * 2);
  u16* h2aH = (u16*)carve((size_t)BB * HD * 2); u16* h2aL = (u16*)carve((size_t)BB * HD * 2);
  u16* h2bH = (u16*)carve((size_t)BB * HD * 2); u16* h2bL = (u16*)carve((size_t)BB * HD * 2);
  float* yfull = (float*)carve((size_t)2 * BB * 4);
  unsigned* gen = (unsigned*)carve(4096);  // 16 group counters, 256-B stride
  auto carve_pack = [&](int K) -> u16* {
    return (u16*)carve((size_t)3 * HD * K * 2 * 2);
  };
  u16* pk_e0ih = carve_pack(DIN);
  u16* pk_e0hh = carve_pack(HD);
  u16* pk_e1ih = carve_pack(HD);
  u16* pk_e1hh = carve_pack(HD);
  u16* pk_d0hh = carve_pack(HD);
  u16* pk_d1ih = carve_pack(HD);
  u16* pk_d1hh = carve_pack(HD);

  hipMemsetAsync(h1aH, 0, (size_t)BB * HD * 2, stream);
  hipMemsetAsync(h1aL, 0, (size_t)BB * HD * 2, stream);
  hipMemsetAsync(h2aH, 0, (size_t)BB * HD * 2, stream);
  hipMemsetAsync(h2aL, 0, (size_t)BB * HD * 2, stream);
  hipMemsetAsync(yfull, 0, (size_t)2 * BB * 4, stream);
  hipMemsetAsync(gen, 0, 4096, stream);

  auto pack = [&](const float* W, int K, u16* dst) {
    int total = 16 * (K >> 5) * 2 * 6 * 64;
    pack_w_kernel<<<(total + 255) / 256, 256, 0, stream>>>(W, K, dst);
  };
  pack(eW_ih0, DIN, pk_e0ih);
  pack(eW_hh0, HD, pk_e0hh);
  pack(eW_ih1, HD, pk_e1ih);
  pack(eW_hh1, HD, pk_e1hh);
  pack(dW_hh0, HD, pk_d0hh);
  pack(dW_ih1, HD, pk_d1ih);
  pack(dW_hh1, HD, pk_d1hh);

  gru_persistent_kernel<<<NBLK, 256, 0, stream>>>(
      x, pk_e0ih, pk_e0hh, eb_ih0, eb_hh0,
      pk_e1ih, pk_e1hh, eb_ih1, eb_hh1,
      pk_d0hh, db_ih0, db_hh0, dW_ih0,
      pk_d1ih, pk_d1hh, db_ih1, db_hh1,
      outW, outb, dstart,
      h1aH, h1aL, h1bH, h1bL, h2aH, h2aL, h2bH, h2bL,
      yfull, out, gen);
}

// Round 8
// 15836.847 us; speedup vs baseline: 1.3141x; 1.0187x over previous
//
#include <hip/hip_runtime.h>

#define HD 512
#define BB 1024
#define TT 512
#define PP 96
#define DIN 32
#define KC_H 16
#define NBLK 256
#define GRPB 16  // blocks per row-group barrier (all 16 jb of one row group)

typedef unsigned short u16;
typedef __attribute__((ext_vector_type(8))) short bf16x8;
typedef __attribute__((ext_vector_type(4))) float f32x4;
typedef __attribute__((address_space(3))) unsigned int lds_u32;
typedef __attribute__((address_space(3))) u16 lds_u16;
typedef __attribute__((address_space(1))) unsigned int glb_u32;

#define WAIT_VM(N) asm volatile("s_waitcnt vmcnt(" #N ")" ::: "memory")
__device__ __forceinline__ void bar_raw() { asm volatile("s_barrier" ::: "memory"); }

template <int N> __device__ __forceinline__ void wvm() {
  if constexpr (N == 0) WAIT_VM(0);
  else if constexpr (N == 2) WAIT_VM(2);
  else if constexpr (N == 4) WAIT_VM(4);
  else if constexpr (N == 5) WAIT_VM(5);
  else if constexpr (N == 10) WAIT_VM(10);
  else if constexpr (N == 13) WAIT_VM(13);
}

__device__ __forceinline__ float bf2f(u16 s) {
  return __uint_as_float(((unsigned)s) << 16);
}
__device__ __forceinline__ u16 f2bf_rne(float f) {
  unsigned u = __float_as_uint(f);
  u += 0x7FFF + ((u >> 16) & 1);
  return (u16)(u >> 16);
}
__device__ __forceinline__ float sigm(float v) { return 1.f / (1.f + __expf(-v)); }
__device__ __forceinline__ float tanh_(float a) {
  return 1.f - 2.f / (__expf(2.f * a) + 1.f);
}

// ---- coherent (L2-bypass) access helpers: sc0 sc1 ----
__device__ __forceinline__ bf16x8 load_sc16(const u16* p) {
  bf16x8 r;
  asm volatile("global_load_dwordx4 %0, %1, off sc0 sc1" : "=&v"(r) : "v"(p) : "memory");
  return r;
}
__device__ __forceinline__ void store_sc_u16(u16* p, unsigned v) {
  asm volatile("global_store_short %0, %1, off sc0 sc1" :: "v"(p), "v"(v) : "memory");
}
__device__ __forceinline__ void store_sc_f32(float* p, float v) {
  asm volatile("global_store_dword %0, %1, off sc0 sc1" :: "v"(p), "v"(v) : "memory");
}
__device__ __forceinline__ float load_sc_f32w(const float* p) {  // load + full wait
  float v;
  asm volatile("global_load_dword %0, %1, off sc0 sc1\ns_waitcnt vmcnt(0)"
               : "=&v"(v) : "v"(p) : "memory");
  return v;
}
__device__ __forceinline__ unsigned load_sc_u32w(const unsigned* p) {
  unsigned v;
  asm volatile("global_load_dword %0, %1, off sc0 sc1\ns_waitcnt vmcnt(0)"
               : "=&v"(v) : "v"(p) : "memory");
  return v;
}
__device__ __forceinline__ void store_h_sc(u16* H, u16* L, size_t idx, float hv) {
  u16 hi = (u16)(__float_as_uint(hv) >> 16);  // trunc; lo corrects
  u16 lo = f2bf_rne(hv - bf2f(hi));
  store_sc_u16(H + idx, (unsigned)hi);
  store_sc_u16(L + idx, (unsigned)lo);
}

// ---- h-state layout: kc-blocked tiles ----
// h[rowg:64][kc:16][rr:16][cc:32] (u16 units per buffer). A wave's per-kc
// A-fragment load (lane(n16,quad) <- rr=n16, cc=quad*8..+8) is then a DENSE
// 1KB block per instruction (n16*64B + quad*16B) instead of 16 rows
// scattered at 1KB stride -> ~8x128B sequential LLC transactions per load
// instead of 16+ scattered ones. Element (row,col) lives at
// (row>>4)*8192 + (col>>5)*512 + (row&15)*32 + (col&31); a block's epilogue
// writes only its own kc=jb tile.

// Pack fp32 weight W[3H x K] into fc-contiguous MFMA B-frag bf16 hi/lo layout:
// group512 = ((jb*KC + kc)*2 + fc)*6 + (g*2 + s);  u16 off = group*512 + lane*8
__global__ void pack_w_kernel(const float* __restrict__ W, int K,
                              u16* __restrict__ out) {
  int tid = blockIdx.x * 256 + threadIdx.x;
  int KC = K >> 5;
  int total = 16 * KC * 2 * 6 * 64;
  if (tid >= total) return;
  int lane = tid & 63;
  int rest = tid >> 6;
  int gs = rest % 6; rest /= 6;
  int fc = rest & 1; rest >>= 1;
  int kc = rest % KC;
  int jb = rest / KC;
  int g = gs >> 1, s = gs & 1;
  int j = jb * 32 + fc * 16 + (lane & 15);
  int k = kc * 32 + (lane >> 4) * 8;
  const float* src = W + (size_t)(g * HD + j) * K + k;
  bf16x8 v;
#pragma unroll
  for (int i = 0; i < 8; ++i) {
    float f = src[i];
    u16 hi = f2bf_rne(f);
    v[i] = (short)((s == 0) ? hi : f2bf_rne(f - bf2f(hi)));
  }
  *(bf16x8*)(out + (size_t)tid * 8) = v;
}

// A fragments for NA distinct A-streams (hi/lo split bf16).
template <int NA> struct AFN { bf16x8 h[NA]; bf16x8 l[NA]; };
template <int NA>
__device__ __forceinline__ void fence_afn(AFN<NA>& a) {
#pragma unroll
  for (int n = 0; n < NA; ++n)
    asm volatile("" : "+v"(a.h[n]), "+v"(a.l[n]));
}

// 9 MFMAs for one (stream, fc) 6KB chunk (6 frag groups of 512 u16).
__device__ __forceinline__ void mfma_kc9(const lds_u16* base, int lane,
                                         bf16x8 ah, bf16x8 al,
                                         f32x4& R, f32x4& Z, f32x4& N) {
  typedef __attribute__((address_space(3))) const bf16x8 lds_bf16x8;
  const lds_u16* p = base + lane * 8;
#pragma unroll
  for (int g = 0; g < 3; ++g) {
    f32x4* a = (g == 0) ? &R : (g == 1) ? &Z : &N;
    bf16x8 whi = *(lds_bf16x8*)(p + (g * 2 + 0) * 512);
    bf16x8 wlo = *(lds_bf16x8*)(p + (g * 2 + 1) * 512);
    *a = __builtin_amdgcn_mfma_f32_16x16x32_bf16(ah, whi, *a, 0, 0, 0);
    *a = __builtin_amdgcn_mfma_f32_16x16x32_bf16(al, whi, *a, 0, 0, 0);
    *a = __builtin_amdgcn_mfma_f32_16x16x32_bf16(ah, wlo, *a, 0, 0, 0);
  }
}
// Global variant for the K=32 x-phase (L2-hot, compiler-managed waits).
__device__ __forceinline__ void mfma_kc9_g(const u16* base, int lane,
                                           bf16x8 ah, bf16x8 al,
                                           f32x4& R, f32x4& Z, f32x4& N) {
  const u16* p = base + lane * 8;
#pragma unroll
  for (int g = 0; g < 3; ++g) {
    f32x4* a = (g == 0) ? &R : (g == 1) ? &Z : &N;
    bf16x8 whi = *(const bf16x8*)(p + (g * 2 + 0) * 512);
    bf16x8 wlo = *(const bf16x8*)(p + (g * 2 + 1) * 512);
    *a = __builtin_amdgcn_mfma_f32_16x16x32_bf16(ah, whi, *a, 0, 0, 0);
    *a = __builtin_amdgcn_mfma_f32_16x16x32_bf16(al, whi, *a, 0, 0, 0);
    *a = __builtin_amdgcn_mfma_f32_16x16x32_bf16(ah, wlo, *a, 0, 0, 0);
  }
}

// Weight-piece mapping shared by prefetch and pipe: NS streams x 12 x 1KB
// pieces; each of 4 waves stages NS*3 pieces per kc.
template <int NS>
__device__ __forceinline__ void piece_map(const u16* const (&Wjb)[NS],
                                          int lane, int wave,
                                          const u16* (&srcB)[NS * 3],
                                          int (&dstO)[NS * 3]) {
#pragma unroll
  for (int i = 0; i < NS * 3; ++i) {
    const int p = wave * (NS * 3) + i;
    const int s = p / 12, r = p % 12, f2 = r / 6, j = r % 6;
    const int co = f2 * 3072 + j * 512;
    srcB[i] = Wjb[s] + co + lane * 8;
    dstO[i] = s * 6144 + co;
  }
}

// Prefetch (barrier-shadow): stage weight kc=0 -> slot0, kc=1 -> slot1 of the
// UPCOMING pipe's ring layout. Weights are read-only, so this is legal before
// the row-group barrier completes.
template <int NS>
__device__ __forceinline__ void stageW2(u16* ringb, const u16* const (&Wjb)[NS],
                                        int lane, int wave) {
  const u16* srcB[NS * 3]; int dstO[NS * 3];
  piece_map<NS>(Wjb, lane, wave, srcB, dstO);
#pragma unroll
  for (int ikc = 0; ikc < 2; ++ikc)
#pragma unroll
    for (int i = 0; i < NS * 3; ++i)
      __builtin_amdgcn_global_load_lds(
          (const glb_u32*)(srcB[i] + (size_t)ikc * 6144),
          (lds_u32*)(ringb + (size_t)ikc * NS * 6144 + dstO[i]), 16, 0, 0);
}

// Multi-stream K=512 GEMM pipe, depth-3 ring, PREFETCHED slots 0,1 (weights
// already in LDS from the barrier-shadow stageW2). Entry issues only the
// A-loads for slots 0,1; steady state = full bundles (NS*3 DMA + 2*NA sc
// A-loads). All 4 waves stage equal piece counts. Raw s_barrier handoff.
template <int NS, int NA>
__device__ __forceinline__ void pipePre(
    u16* ringb,
    const u16* const (&Ahi)[NA], const u16* const (&Alo)[NA],
    const u16* const (&Wjb)[NS], const int (&ai)[NS],
    f32x4* (&acc)[NS][3],   // acc[s] = {R,Z,N}, each -> f32x4[2] (fc)
    int row0w, int lane, int wave) {
  constexpr int B = NS * 3 + 2 * NA;
  constexpr int A2 = 2 * NA;
  constexpr int SLOT = NS * 6144;
  const int quad = lane >> 4, n16 = lane & 15;
  // kc-blocked A base: rowg tile + rr=n16 + cc=quad*8; step 512 u16 per kc.
  const u16* aH[NA]; const u16* aL[NA];
#pragma unroll
  for (int n = 0; n < NA; ++n) {
    const size_t base = (size_t)(row0w >> 4) * (KC_H * 512) + n16 * 32 + quad * 8;
    aH[n] = Ahi[n] + base;
    aL[n] = Alo[n] + base;
  }
  const u16* srcB[NS * 3]; int dstO[NS * 3];
  piece_map<NS>(Wjb, lane, wave, srcB, dstO);
  u16* pb[3] = {ringb, ringb + SLOT, ringb + 2 * SLOT};
  AFN<NA> af0, af1, af2;

  auto issueA = [&](int ikc, AFN<NA>& dst) {
#pragma unroll
    for (int n = 0; n < NA; ++n) {
      dst.h[n] = load_sc16(aH[n] + ikc * 512);
      dst.l[n] = load_sc16(aL[n] + ikc * 512);
    }
  };
  auto issueB = [&](int ikc, int si, AFN<NA>& dst) {
#pragma unroll
    for (int i = 0; i < NS * 3; ++i)
      __builtin_amdgcn_global_load_lds(
          (const glb_u32*)(srcB[i] + (size_t)ikc * 6144),
          (lds_u32*)(pb[si] + dstO[i]), 16, 0, 0);
    issueA(ikc, dst);
  };
  auto cons = [&](int si, AFN<NA>& a) {
    fence_afn(a);
#pragma unroll
    for (int s = 0; s < NS; ++s)
#pragma unroll
      for (int f = 0; f < 2; ++f)
        mfma_kc9((const lds_u16*)(pb[si] + s * 6144 + f * 3072), lane,
                 a.h[ai[s]], a.l[ai[s]],
                 acc[s][0][f], acc[s][1][f], acc[s][2][f]);
  };

  WAIT_VM(0);  // drain own prefetch DMAs (slots 0,1 weights)
  issueA(0, af0);
  issueA(1, af1);
  wvm<A2>(); bar_raw(); issueB(2, 2, af2); cons(0, af0);   // kc=0
  wvm<B>();  bar_raw(); issueB(3, 0, af0); cons(1, af1);   // kc=1
#pragma unroll 1
  for (int q = 0; q < 4; ++q) {  // covers kc 2..13
    const int base = 4 + q * 3;  // ikc of first issue
    wvm<B>(); bar_raw(); issueB(base + 0, 1, af1); cons(2, af2);
    wvm<B>(); bar_raw(); issueB(base + 1, 2, af2); cons(0, af0);
    wvm<B>(); bar_raw(); issueB(base + 2, 0, af0); cons(1, af1);
  }
  wvm<B>(); bar_raw(); cons(2, af2);   // kc=14
  wvm<0>(); bar_raw(); cons(0, af0);   // kc=15
}

// x-accumulate for encoder L0: fp32 x[B,T,32], K=32, weights/x normal
// (L2-hot). Runs in the barrier shadow; accumulates into xR/xZ/xN.
__device__ __forceinline__ void x_acc(const float* x, int t, const u16* Wp,
                                      int jb, int row0w, int lane,
                                      f32x4* aR, f32x4* aZ, f32x4* aN) {
  const int quad = lane >> 4, n16 = lane & 15;
  const float* xp = x + (size_t)(row0w + n16) * (TT * DIN) +
                    (size_t)t * DIN + quad * 8;
  f32x4 v0 = *(const f32x4*)xp;
  f32x4 v1 = *(const f32x4*)(xp + 4);
  bf16x8 hi, lo;
#pragma unroll
  for (int i = 0; i < 8; ++i) {
    float f = (i < 4) ? v0[i] : v1[i - 4];
    u16 h = (u16)(__float_as_uint(f) >> 16);
    hi[i] = (short)h;
    lo[i] = (short)f2bf_rne(f - bf2f(h));
  }
#pragma unroll
  for (int f = 0; f < 2; ++f)
    mfma_kc9_g(Wp + ((size_t)jb * 2 + f) * 3072, lane, hi, lo,
               aR[f], aZ[f], aN[f]);
}

// Row-group barrier, split arrive/wait: the window between them is filled
// with next-step weight prefetch + x-phase (peer-independent work).
__device__ __forceinline__ void gbar_arrive(unsigned* gen) {
  WAIT_VM(0);  // all this wave's sc1 stores / atomics globally visible
  __syncthreads();
  if (threadIdx.x == 0) atomicAdd(gen, 1u);  // device-scope by default
}
__device__ __forceinline__ void gbar_wait(unsigned* gen, unsigned target) {
  if (threadIdx.x == 0) {
    while (load_sc_u32w(gen) < target) __builtin_amdgcn_s_sleep(2);
  }
  __syncthreads();
}

// GRU epilogue with register-resident own-tile h. Stores go to the wave's
// own kc=jb tile in the kc-blocked layout.
__device__ __forceinline__ void gru_epi_reg(
    const float* bi, const float* bh, float (*ht)[4],
    u16* hnH, u16* hnL, int jb, int col0, int row0w, int quad, int n16,
    const f32x4* aR, const f32x4* aZ, const f32x4* aNX, const f32x4* aNH) {
  const size_t hb = ((size_t)(row0w >> 4) * KC_H + jb) * 512;
#pragma unroll
  for (int f = 0; f < 2; ++f) {
    const int col = col0 + f * 16;
    const float bir = bi[col],          bhr = bh[col];
    const float biz = bi[HD + col],     bhz = bh[HD + col];
    const float bin = bi[2 * HD + col], bhn = bh[2 * HD + col];
#pragma unroll
    for (int r = 0; r < 4; ++r) {
      const size_t idx = hb + (quad * 4 + r) * 32 + f * 16 + n16;
      float rr = sigm(aR[f][r] + bir + bhr);
      float zz = sigm(aZ[f][r] + biz + bhz);
      float nn = tanh_(aNX[f][r] + bin + rr * (aNH[f][r] + bhn));
      float hv = (1.f - zz) * nn + zz * ht[f][r];
      ht[f][r] = hv;
      store_h_sc(hnH, hnL, idx, hv);
    }
  }
}

__global__ __launch_bounds__(256, 1)
void gru_persistent_kernel(
    const float* x,
    const u16* pkX0, const u16* pkH0, const float* bi0, const float* bh0,
    const u16* pkX1, const u16* pkH1, const float* bi1, const float* bh1,
    const u16* pkD0H, const float* dbi0, const float* dbh0, const float* dW0,
    const u16* pkD1I, const u16* pkD1H, const float* dbi1, const float* dbh1,
    const float* outW, const float* outb, const float* dstart,
    u16* h1aH, u16* h1aL, u16* h1bH, u16* h1bL,
    u16* h2aH, u16* h2aL, u16* h2bH, u16* h2bL,
    float* yfull, float* dout, unsigned* gen) {
  __shared__ u16 ring[3 * 3 * 6144];  // 108 KB: 3-slot triple-stream ring
  const int b = blockIdx.x;
  const int jb = (b & 7) * 2 + ((b >> 3) & 1);  // XCD-local jb
  const int row0 = (b >> 4) * 64;
  const int tid = threadIdx.x, wave = tid >> 6, lane = tid & 63;
  const int quad = lane >> 4, n16 = lane & 15;
  const int row0w = row0 + wave * 16;  // 4 waves = 4 row groups
  const int col0 = jb * 32 + n16;
  u16* ringb = &ring[0];
  const f32x4 z4 = {0.f, 0.f, 0.f, 0.f};
  const size_t jbs = (size_t)jb * (KC_H * 2 * 3072);  // jb slice base (K=512)
  const u16* pkH0j = pkH0 + jbs;
  const u16* pkX1j = pkX1 + jbs;
  const u16* pkH1j = pkH1 + jbs;
  const u16* pkD0Hj = pkD0H + jbs;
  const u16* pkD1Ij = pkD1I + jbs;
  const u16* pkD1Hj = pkD1H + jbs;
  // Per-row-group barrier counter: one u32 per group, 256-B line separation.
  unsigned* geng = gen + ((b >> 4) << 6);

  u16 *h1cH = h1aH, *h1cL = h1aL, *h1nH = h1bH, *h1nL = h1bL;
  u16 *h2cH = h2aH, *h2cL = h2aL, *h2nH = h2bH, *h2nL = h2bL;
  float ht1[2][4] = {{0, 0, 0, 0}, {0, 0, 0, 0}};  // own h1 tile (fc, r)
  float ht2[2][4] = {{0, 0, 0, 0}, {0, 0, 0, 0}};  // own h2 tile (fc, r)
  unsigned it = 0;

  // x-phase accumulators for the upcoming encoder step (barrier-shadow).
  f32x4 xR[2] = {z4, z4}, xZ[2] = {z4, z4}, xN[2] = {z4, z4};
  {  // initial prefetch for k=0 single pipe + x-acc(0)
    const u16* Wv1[1] = {pkH0j};
    stageW2<1>(ringb, Wv1, lane, wave);
    x_acc(x, 0, pkX0, jb, row0w, lane, xR, xZ, xN);
  }

  // ---- encoder: 513 skewed phases; ONE merged pipe per step ----
  for (int k = 0; k <= TT; ++k) {
    f32x4 R0[2], Z0[2], NX0[2], NH0[2] = {z4, z4};
    f32x4 R1[2] = {z4, z4}, Z1[2] = {z4, z4}, NX1[2] = {z4, z4}, NH1[2] = {z4, z4};
    if (k < TT) {
      R0[0] = xR[0]; R0[1] = xR[1];
      Z0[0] = xZ[0]; Z0[1] = xZ[1];
      NX0[0] = xN[0]; NX0[1] = xN[1];
    } else {
      R0[0] = z4; R0[1] = z4; Z0[0] = z4; Z0[1] = z4; NX0[0] = z4; NX0[1] = z4;
    }
    if (k > 0 && k < TT) {
      // Triple: L0-h (pkH0*h1), L1-x (pkX1*h1), L1-h (pkH1*h2).
      const u16* Ah[2] = {h1cH, h2cH};
      const u16* Al[2] = {h1cL, h2cL};
      const u16* Wv[3] = {pkH0j, pkX1j, pkH1j};
      const int ai3[3] = {0, 0, 1};
      f32x4* ac[3][3] = {{R0, Z0, NH0}, {R1, Z1, NX1}, {R1, Z1, NH1}};
      pipePre<3, 2>(ringb, Ah, Al, Wv, ai3, ac, row0w, lane, wave);
    } else if (k == 0) {
      const u16* Ah[1] = {h1cH};
      const u16* Al[1] = {h1cL};
      const u16* Wv[1] = {pkH0j};
      const int ai1[1] = {0};
      f32x4* ac[1][3] = {{R0, Z0, NH0}};
      pipePre<1, 1>(ringb, Ah, Al, Wv, ai1, ac, row0w, lane, wave);
    } else {  // k == TT: L1-x + L1-h only
      const u16* Ah[2] = {h1cH, h2cH};
      const u16* Al[2] = {h1cL, h2cL};
      const u16* Wv[2] = {pkX1j, pkH1j};
      const int ai2[2] = {0, 1};
      f32x4* ac[2][3] = {{R1, Z1, NX1}, {R1, Z1, NH1}};
      pipePre<2, 2>(ringb, Ah, Al, Wv, ai2, ac, row0w, lane, wave);
    }
    if (k < TT)
      gru_epi_reg(bi0, bh0, ht1, h1nH, h1nL, jb, col0, row0w, quad, n16,
                  R0, Z0, NX0, NH0);
    if (k > 0)
      gru_epi_reg(bi1, bh1, ht2, h2nH, h2nL, jb, col0, row0w, quad, n16,
                  R1, Z1, NX1, NH1);
    ++it;
    gbar_arrive(geng);
    // ---- barrier shadow: peer-independent work ----
    if (k + 1 < TT) {
      xR[0] = z4; xR[1] = z4; xZ[0] = z4; xZ[1] = z4; xN[0] = z4; xN[1] = z4;
      x_acc(x, k + 1, pkX0, jb, row0w, lane, xR, xZ, xN);
    }
    if (k + 1 < TT) {
      const u16* Wv3[3] = {pkH0j, pkX1j, pkH1j};
      stageW2<3>(ringb, Wv3, lane, wave);
    } else if (k + 1 == TT) {
      const u16* Wv2[2] = {pkX1j, pkH1j};
      stageW2<2>(ringb, Wv2, lane, wave);
    } else {  // k == TT -> next is decoder L0 (single)
      const u16* Wv1[1] = {pkD0Hj};
      stageW2<1>(ringb, Wv1, lane, wave);
    }
    gbar_wait(geng, GRPB * it);
    if (k < TT) { u16* t0 = h1cH; h1cH = h1nH; h1nH = t0;
                  u16* t1 = h1cL; h1cL = h1nL; h1nL = t1; }
    if (k > 0)  { u16* t0 = h2cH; h2cH = h2nH; h2nH = t0;
                  u16* t1 = h2cL; h2cL = h2nL; h2nL = t1; }
  }

  // ---- decoder: 96 steps x (L0, L1); y via atomics into yfull[2][BB] ----
  for (int t = 0; t < PP; ++t) {
    {  // dec L0
      f32x4 R[2] = {z4, z4}, Z[2] = {z4, z4}, NH[2] = {z4, z4};
      {
        const u16* Ah[1] = {h1cH};
        const u16* Al[1] = {h1cL};
        const u16* Wv[1] = {pkD0Hj};
        const int ai1[1] = {0};
        f32x4* ac[1][3] = {{R, Z, NH}};
        pipePre<1, 1>(ringb, Ah, Al, Wv, ai1, ac, row0w, lane, wave);
      }
      float yl[4] = {0, 0, 0, 0};
      if (t > 0) {
        const float* yb = yfull + ((t - 1) & 1) * BB;
#pragma unroll
        for (int r = 0; r < 4; ++r) {
          const float* p = yb + (row0w + quad * 4 + r);
          asm volatile("global_load_dword %0, %1, off sc0 sc1"
                       : "=&v"(yl[r]) : "v"(p) : "memory");
        }
        WAIT_VM(0);
#pragma unroll
        for (int r = 0; r < 4; ++r)
          asm volatile("" : "+v"(yl[r]));
      }
      const float ds0 = dstart[0], ob0 = outb[0];
      const size_t hb = ((size_t)(row0w >> 4) * KC_H + jb) * 512;
#pragma unroll
      for (int f = 0; f < 2; ++f) {
        const int col = col0 + f * 16;
        const float bir = dbi0[col],          bhr = dbh0[col];
        const float biz = dbi0[HD + col],     bhz = dbh0[HD + col];
        const float bin = dbi0[2 * HD + col], bhn = dbh0[2 * HD + col];
        const float w0r = dW0[col], w0z = dW0[HD + col], w0n = dW0[2 * HD + col];
#pragma unroll
        for (int r = 0; r < 4; ++r) {
          const int row = row0w + quad * 4 + r;
          const size_t idx = hb + (quad * 4 + r) * 32 + f * 16 + n16;
          float yv = (t == 0) ? ds0 : (ob0 + yl[r]);
          if (f == 0 && t > 0 && jb == 0 && n16 == 0)
            dout[(size_t)row * PP + (t - 1)] = yv;
          float rr = sigm(R[f][r] + bir + bhr + yv * w0r);
          float zz = sigm(Z[f][r] + biz + bhz + yv * w0z);
          float nn = tanh_(bin + yv * w0n + rr * (NH[f][r] + bhn));
          float hv = (1.f - zz) * nn + zz * ht1[f][r];
          ht1[f][r] = hv;
          store_h_sc(h1nH, h1nL, idx, hv);
        }
      }
    }
    ++it;
    gbar_arrive(geng);
    {  // barrier shadow: prefetch dual {D1I, D1H}
      const u16* Wv2[2] = {pkD1Ij, pkD1Hj};
      stageW2<2>(ringb, Wv2, lane, wave);
    }
    gbar_wait(geng, GRPB * it);
    {  // dec L1: merged dual pipe (pkD1I*h1n + pkD1H*h2c)
      f32x4 R[2] = {z4, z4}, Z[2] = {z4, z4}, NX[2] = {z4, z4}, NH[2] = {z4, z4};
      {
        const u16* Ah[2] = {h1nH, h2cH};
        const u16* Al[2] = {h1nL, h2cL};
        const u16* Wv[2] = {pkD1Ij, pkD1Hj};
        const int ai2[2] = {0, 1};
        f32x4* ac[2][3] = {{R, Z, NX}, {R, Z, NH}};
        pipePre<2, 2>(ringb, Ah, Al, Wv, ai2, ac, row0w, lane, wave);
      }
      float vs[4] = {0, 0, 0, 0};
      const size_t hb = ((size_t)(row0w >> 4) * KC_H + jb) * 512;
#pragma unroll
      for (int f = 0; f < 2; ++f) {
        const int col = col0 + f * 16;
        const float bir = dbi1[col],          bhr = dbh1[col];
        const float biz = dbi1[HD + col],     bhz = dbh1[HD + col];
        const float bin = dbi1[2 * HD + col], bhn = dbh1[2 * HD + col];
        const float wo = outW[col];
#pragma unroll
        for (int r = 0; r < 4; ++r) {
          const size_t idx = hb + (quad * 4 + r) * 32 + f * 16 + n16;
          float rr = sigm(R[f][r] + bir + bhr);
          float zz = sigm(Z[f][r] + biz + bhz);
          float nn = tanh_(NX[f][r] + bin + rr * (NH[f][r] + bhn));
          float hv = (1.f - zz) * nn + zz * ht2[f][r];
          ht2[f][r] = hv;
          store_h_sc(h2nH, h2nL, idx, hv);
          float v = hv * wo;
#pragma unroll
          for (int off = 1; off < 16; off <<= 1) v += __shfl_xor(v, off, 16);
          vs[r] += v;
        }
      }
      float* yw = yfull + (t & 1) * BB;
      float* yz = yfull + ((t - 1) & 1) * BB;
#pragma unroll
      for (int r = 0; r < 4; ++r) {
        const int row = row0w + quad * 4 + r;
        if (n16 == 0) {
          atomicAdd(yw + row, vs[r]);
          // zero last parity (read by dec L0 this iter; rewritten at t+1)
          if (t > 0 && jb == 0) store_sc_f32(yz + row, 0.f);
        }
      }
    }
    ++it;
    gbar_arrive(geng);
    if (t + 1 < PP) {  // barrier shadow: prefetch next dec L0 single
      const u16* Wv1[1] = {pkD0Hj};
      stageW2<1>(ringb, Wv1, lane, wave);
    }
    gbar_wait(geng, GRPB * it);
    { u16* t0 = h1cH; h1cH = h1nH; h1nH = t0;
      u16* t1 = h1cL; h1cL = h1nL; h1nL = t1; }
    { u16* t0 = h2cH; h2cH = h2nH; h2nH = t0;
      u16* t1 = h2cL; h2cL = h2nL; h2nL = t1; }
  }

  // ---- finalize: y(P-1), group-local (each group's jb==0 block owns its
  // 64 rows; last gbar guarantees peer atomicAdds are visible) ----
  if ((b & 15) == 0 && tid < 64) {
    int row = row0 + tid;
    float v = load_sc_f32w(yfull + ((PP - 1) & 1) * BB + row);
    dout[(size_t)row * PP + (PP - 1)] = outb[0] + v;
  }
}

extern "C" void kernel_launch(void* const* d_in, const int* in_sizes, int n_in,
                              void* d_out, int out_size, void* d_ws, size_t ws_size,
                              hipStream_t stream) {
  const float* x      = (const float*)d_in[0];
  const float* eW_ih0 = (const float*)d_in[1];
  const float* eW_hh0 = (const float*)d_in[2];
  const float* eb_ih0 = (const float*)d_in[3];
  const float* eb_hh0 = (const float*)d_in[4];
  const float* eW_ih1 = (const float*)d_in[5];
  const float* eW_hh1 = (const float*)d_in[6];
  const float* eb_ih1 = (const float*)d_in[7];
  const float* eb_hh1 = (const float*)d_in[8];
  const float* dW_ih0 = (const float*)d_in[9];
  const float* dW_hh0 = (const float*)d_in[10];
  const float* db_ih0 = (const float*)d_in[11];
  const float* db_hh0 = (const float*)d_in[12];
  const float* dW_ih1 = (const float*)d_in[13];
  const float* dW_hh1 = (const float*)d_in[14];
  const float* db_ih1 = (const float*)d_in[15];
  const float* db_hh1 = (const float*)d_in[16];
  const float* outW   = (const float*)d_in[17];
  const float* outb   = (const float*)d_in[18];
  const float* dstart = (const float*)d_in[19];
  float* out = (float*)d_out;

  char* w = (char*)d_ws;
  size_t off = 0;
  auto carve = [&](size_t bytes) -> void* {
    void* p = w + off;
    off = (off + bytes + 255) & ~(size_t)255;
    return p;
  };
  u16* h1aH = (u16*)carve((size_t)BB * HD * 2); u16* h1aL = (u16*)carve((size_t)BB * HD * 2);
  u16* h1bH = (u16*)carve((size_t)BB * HD * 2); u16* h1bL = (u16*)carve((size_t)BB * HD * 2);
  u16* h2aH = (u16*)carve((size_t)BB * HD * 2); u16* h2aL = (u16*)carve((size_t)BB * HD * 2);
  u16* h2bH = (u16*)carve((size_t)BB * HD * 2); u16* h2bL = (u16*)carve((size_t)BB * HD * 2);
  float* yfull = (float*)carve((size_t)2 * BB * 4);
  unsigned* gen = (unsigned*)carve(4096);  // 16 group counters, 256-B stride
  auto carve_pack = [&](int K) -> u16* {
    return (u16*)carve((size_t)3 * HD * K * 2 * 2);
  };
  u16* pk_e0ih = carve_pack(DIN);
  u16* pk_e0hh = carve_pack(HD);
  u16* pk_e1ih = carve_pack(HD);
  u16* pk_e1hh = carve_pack(HD);
  u16* pk_d0hh = carve_pack(HD);
  u16* pk_d1ih = carve_pack(HD);
  u16* pk_d1hh = carve_pack(HD);

  hipMemsetAsync(h1aH, 0, (size_t)BB * HD * 2, stream);
  hipMemsetAsync(h1aL, 0, (size_t)BB * HD * 2, stream);
  hipMemsetAsync(h2aH, 0, (size_t)BB * HD * 2, stream);
  hipMemsetAsync(h2aL, 0, (size_t)BB * HD * 2, stream);
  hipMemsetAsync(yfull, 0, (size_t)2 * BB * 4, stream);
  hipMemsetAsync(gen, 0, 4096, stream);

  auto pack = [&](const float* W, int K, u16* dst) {
    int total = 16 * (K >> 5) * 2 * 6 * 64;
    pack_w_kernel<<<(total + 255) / 256, 256, 0, stream>>>(W, K, dst);
  };
  pack(eW_ih0, DIN, pk_e0ih);
  pack(eW_hh0, HD, pk_e0hh);
  pack(eW_ih1, HD, pk_e1ih);
  pack(eW_hh1, HD, pk_e1hh);
  pack(dW_hh0, HD, pk_d0hh);
  pack(dW_ih1, HD, pk_d1ih);
  pack(dW_hh1, HD, pk_d1hh);

  gru_persistent_kernel<<<NBLK, 256, 0, stream>>>(
      x, pk_e0ih, pk_e0hh, eb_ih0, eb_hh0,
      pk_e1ih, pk_e1hh, eb_ih1, eb_hh1,
      pk_d0hh, db_ih0, db_hh0, dW_ih0,
      pk_d1ih, pk_d1hh, db_ih1, db_hh1,
      outW, outb, dstart,
      h1aH, h1aL, h1bH, h1bL, h2aH, h2aL, h2bH, h2bL,
      yfull, out, gen);
}